// Round 1
// baseline (224.194 us; speedup 1.0000x reference)
//
#include <hip/hip_runtime.h>
#include <hip/hip_bf16.h>
#include <math.h>

static constexpr int N_NODES = 20000;
static constexpr int N_EDGES = 320000;
static constexpr int ETOT    = N_EDGES + N_NODES;   // edges + self loops
static constexpr float LN_EPS = 1e-5f;

__device__ __forceinline__ float lrelu02(float x){ return x > 0.f ? x : 0.2f*x; }
__device__ __forceinline__ float gelu_ex(float x){ return 0.5f*x*(1.f+erff(x*0.70710678118654752f)); }
__device__ __forceinline__ float bflo(unsigned u){ return __uint_as_float(u<<16); }
__device__ __forceinline__ float bfhi(unsigned u){ return __uint_as_float(u & 0xffff0000u); }
__device__ __forceinline__ unsigned f2bf(float f){           // RNE fp32->bf16
  unsigned u = __float_as_uint(f);
  return (u + 0x7fffu + ((u>>16)&1u)) >> 16;
}
__device__ __forceinline__ unsigned packbf2(float a, float b){ return f2bf(a) | (f2bf(b)<<16); }

typedef __attribute__((ext_vector_type(8))) short bf16x8;
typedef __attribute__((ext_vector_type(4))) float f32x4;
union BF8 { unsigned short us[8]; bf16x8 v; uint4 u4; };

// ---- prep: weight transposes + PARALLEL w~ + zero cnt ----
static constexpr int TB1 = 512*128/256;             // 256 blocks W1t
static constexpr int TB2 = 512*128/256;             // 256 blocks W2t
static constexpr int WTB = 128;                     // 128 blocks wtil (8 outs ea, 32 thr/out)
static constexpr int ZCB = (N_NODES + 255)/256;     // 79 blocks zero-cnt
__global__ __launch_bounds__(256) void k_prep(
    const float* __restrict__ W1, const float* __restrict__ W2,
    const float* __restrict__ att1_s, const float* __restrict__ att1_d,
    unsigned short* __restrict__ W1t, unsigned short* __restrict__ W2t,
    float* __restrict__ wtil, int* __restrict__ cnt) {
  int b = blockIdx.x, tid = threadIdx.x;
  if (b < TB1){                                     // W1t[n][k]=bf16(W1[k][n]) K=128,N=512
    int idx = b*256 + tid;
    int n = idx >> 7, k = idx & 127;
    W1t[idx] = (unsigned short)f2bf(W1[(size_t)k*512 + n]);
    return;
  }
  if (b < TB1 + TB2){                               // W2t[n][k]=bf16(W2[k][n]) K=512,N=128
    int idx = (b-TB1)*256 + tid;
    int n = idx >> 9, k = idx & 511;
    W2t[idx] = (unsigned short)f2bf(W2[(size_t)k*128 + n]);
    return;
  }
  if (b < TB1 + TB2 + WTB){
    // wtil[v*128+k] = sum_c W1[k, (v&3)*128+c]*att{s|d}[(v&3),c]; 32 thr/output
    int o = (b-TB1-TB2)*8 + (tid>>5);               // 0..1023
    int c32 = tid & 31;
    int v = o >> 7, k = o & 127, h = v & 3;
    const float* av = (v < 4) ? (att1_s + h*128) : (att1_d + h*128);
    const float* wr = W1 + (size_t)k*512 + h*128;
    float p = wr[c32]*av[c32] + wr[c32+32]*av[c32+32]
            + wr[c32+64]*av[c32+64] + wr[c32+96]*av[c32+96];
    #pragma unroll
    for (int o2=1;o2<32;o2<<=1) p += __shfl_xor(p, o2);
    if (c32 == 0) wtil[o] = p;
    return;
  }
  int idx = (b - TB1 - TB2 - WTB)*256 + tid;        // zero cnt
  if (idx < N_NODES) cnt[idx] = 0;
}

// ---- mega kernel: ELL build (atomic slots) + input LN + fp32 att1 logits ----
static constexpr int EBL = (ETOT + 255)/256;        // 1329 edge blocks
static constexpr int LNB = N_NODES/4;               // 5000 LN blocks (4 rows ea)
__global__ __launch_bounds__(256) void k_build_mega(
    const int* __restrict__ ei, int* __restrict__ cnt, int* __restrict__ ell,
    const float* __restrict__ x, const float* __restrict__ g_in,
    const float* __restrict__ b_in, const float* __restrict__ wtil,
    unsigned* __restrict__ h0b, float4* __restrict__ als4, float4* __restrict__ ald4) {
  int b = blockIdx.x, tid = threadIdx.x;
  if (b < EBL){                                     // ELL scatter (deg<=64 w.h.p.)
    int e = b*256 + tid;
    int s, d;
    if (e < N_EDGES){ s = ei[e]; d = ei[N_EDGES+e]; }
    else if (e < ETOT){ s = e - N_EDGES; d = s; }
    else return;
    int pos = atomicAdd(&cnt[d], 1);
    if (pos < 64) ell[d*64 + pos] = s;
    return;
  }
  // LN over 128-ch rows -> bf16 h0b; logits als/ald = h0 . w~ (fp32 exact)
  int row = (b - EBL)*4 + (tid>>6);
  int t = tid & 63;
  float2 v = ((const float2*)(x + (size_t)row*128))[t];
  float s = v.x + v.y;
  #pragma unroll
  for (int o=32;o>0;o>>=1) s += __shfl_down(s,o);
  s = __shfl(s,0);
  float mu = s*(1.f/128.f);
  float d0 = v.x-mu, d1 = v.y-mu;
  float q = d0*d0+d1*d1;
  #pragma unroll
  for (int o=32;o>0;o>>=1) q += __shfl_down(q,o);
  q = __shfl(q,0);
  float rs = rsqrtf(q*(1.f/128.f)+LN_EPS);
  float2 gg = ((const float2*)g_in)[t];
  float2 bb = ((const float2*)b_in)[t];
  float y0 = d0*rs*gg.x+bb.x;
  float y1 = d1*rs*gg.y+bb.y;
  h0b[(size_t)row*64 + t] = packbf2(y0,y1);
  float ps[4], pd[4];
  #pragma unroll
  for (int h=0;h<4;h++){
    float2 ws = ((const float2*)(wtil + h*128))[t];
    float2 wd = ((const float2*)(wtil + (4+h)*128))[t];
    ps[h] = y0*ws.x + y1*ws.y;
    pd[h] = y0*wd.x + y1*wd.y;
  }
  #pragma unroll
  for (int o=1;o<64;o<<=1){
    #pragma unroll
    for (int h=0;h<4;h++){ ps[h]+=__shfl_xor(ps[h],o); pd[h]+=__shfl_xor(pd[h],o); }
  }
  if (t==0){
    als4[row] = make_float4(ps[0],ps[1],ps[2],ps[3]);
    ald4[row] = make_float4(pd[0],pd[1],pd[2],pd[3]);
  }
}

// ---- GAT1 in input space + W1-proj MFMA + LN/GELU + GEMM2 + att2 ----
// r15: 512 threads / 8 waves per block (was 256/4). Same 16 dst/block, but each
// wave now owns 2 dst rounds instead of 4 -> Phase A critical path halves; the
// MFMA/LN/GEMM2 phases split over 8 waves (acc1 shrinks 32->16 VGPRs). Grid,
// LDS ceiling and waves/CU potential unchanged; block makespan ~halves.
__global__ __launch_bounds__(512) void k_gat1_fused(
    const unsigned* __restrict__ h0,                 // [N][64] uint = [N,128] bf16
    const float4* __restrict__ als4, const float4* __restrict__ ald4, // [N]
    const int* __restrict__ cnt, const int* __restrict__ ell,
    const float* __restrict__ bias1, const float* __restrict__ g1, const float* __restrict__ b1,
    const unsigned short* __restrict__ W1t,          // [512][128] bf16
    const unsigned short* __restrict__ W2t,          // [128][512] bf16
    const float* __restrict__ att2_s, const float* __restrict__ att2_d, // [128]
    unsigned short* __restrict__ xh2b,               // [N,128] bf16
    float* __restrict__ als2, float* __restrict__ ald2) // [N]
{
  __shared__ unsigned short AggHi[16*520];           // reused as h1 tile later
  __shared__ float4 alphaW4[8][64];                  // 4 head-alphas packed per slot
  __shared__ int   srcW[8][64];
  __shared__ float scrA[8][16], scrB[8][16];
  __shared__ float scrS[8][16], scrD[8][16];
  int dstbase = blockIdx.x*16;
  int tid = threadIdx.x, wave = tid>>6, lane = tid&63;
  int kq = lane>>4, l15 = lane&15;

  // ---- Phase A: descriptors upfront (cheap), als4 staged 1-deep ----
  int degP[2], sP[2];
  float4 adP[2];
  #pragma unroll
  for (int r=0;r<2;r++){
    int d = dstbase + r*8 + wave;
    degP[r] = min(cnt[d],64);
    sP[r]   = ell[d*64 + lane];                      // unconditional
    adP[r]  = ald4[d];
  }
  #pragma unroll
  for (int r=0;r<2;r++) sP[r] = (lane < degP[r]) ? sP[r] : 0;
  float4 asCur = als4[sP[0]];

  unsigned* Hi = (unsigned*)AggHi;
  #pragma unroll
  for (int r=0; r<2; r++){
    float4 asNext;
    if (r < 1) asNext = als4[sP[1]];                 // in flight during this round
    int row = r*8 + wave;                            // 0..15
    int deg = degP[r];
    float4 ad_ = adP[r];
    float e0=0.f,e1=0.f,e2=0.f,e3=0.f;
    if (lane < deg){
      e0 = __expf(lrelu02(asCur.x+ad_.x));
      e1 = __expf(lrelu02(asCur.y+ad_.y));
      e2 = __expf(lrelu02(asCur.z+ad_.z));
      e3 = __expf(lrelu02(asCur.w+ad_.w));
    }
    srcW[wave][lane] = sP[r];
    alphaW4[wave][lane] = make_float4(e0,e1,e2,e3);
    float q0=e0,q1=e1,q2=e2,q3=e3;
    #pragma unroll
    for (int o=1;o<64;o<<=1){
      q0+=__shfl_xor(q0,o); q1+=__shfl_xor(q1,o);
      q2+=__shfl_xor(q2,o); q3+=__shfl_xor(q3,o);
    }
    float inv[4] = {1.f/q0, 1.f/q1, 1.f/q2, 1.f/q3};

    float acc[8] = {};                               // [head*2 + (lo,hi)]
    int degR = (deg + 7) & ~7;
    for (int j=0; j<degR; j+=8){                     // 8 loads in flight
      int4 sA4 = *(const int4*)&srcW[wave][j];       // packed src reads
      int4 sB4 = *(const int4*)&srcW[wave][j+4];
      unsigned v[8];
      v[0] = h0[(size_t)sA4.x*64 + lane];
      v[1] = h0[(size_t)sA4.y*64 + lane];
      v[2] = h0[(size_t)sA4.z*64 + lane];
      v[3] = h0[(size_t)sA4.w*64 + lane];
      v[4] = h0[(size_t)sB4.x*64 + lane];
      v[5] = h0[(size_t)sB4.y*64 + lane];
      v[6] = h0[(size_t)sB4.z*64 + lane];
      v[7] = h0[(size_t)sB4.w*64 + lane];
      #pragma unroll
      for (int i=0;i<8;i++){
        float4 a = alphaW4[wave][j+i];               // ONE b128 broadcast/edge
        float lo = bflo(v[i]), hi = bfhi(v[i]);
        acc[0]+=a.x*lo; acc[1]+=a.x*hi;
        acc[2]+=a.y*lo; acc[3]+=a.y*hi;
        acc[4]+=a.z*lo; acc[5]+=a.z*hi;
        acc[6]+=a.w*lo; acc[7]+=a.w*hi;
      }
    }
    // normalize; lane owns ch pair (2*lane, 2*lane+1) per head; bf16 pack
    #pragma unroll
    for (int h=0; h<4; h++){
      float x0 = acc[2*h]*inv[h], x1 = acc[2*h+1]*inv[h];
      Hi[row*260 + h*64 + lane] = packbf2(x0,x1);
    }
    if (r < 1) asCur = asNext;
  }
  __syncthreads();

  // ---- Phase B: W1 projection; wave covers cols [wave*64, wave*64+64), head = wave>>1 ----
  f32x4 acc1[4] = {};
  {
    const uint4* Hi4 = (const uint4*)AggHi;
    int h = wave>>1;
    #pragma unroll
    for (int kt=0; kt<4; kt++){
      BF8 fh;
      fh.u4 = Hi4[(size_t)l15*65 + h*16 + kt*4 + kq];
      #pragma unroll
      for (int ct=0; ct<4; ct++){
        int col = wave*64 + ct*16 + l15;
        BF8 fb; fb.u4 = *(const uint4*)&W1t[(size_t)col*128 + kt*32 + kq*8];
        acc1[ct] = __builtin_amdgcn_mfma_f32_16x16x32_bf16(fh.v, fb.v, acc1[ct], 0,0,0);
      }
    }
  }
  // epilogue: bias + LN(512) + GELU; C layout: m = kq*4+r, col = wave*64+ct*16+l15
  float vloc[4][4];
  float sum_r[4] = {0,0,0,0};
  #pragma unroll
  for (int ct=0; ct<4; ct++){
    int col = wave*64 + ct*16 + l15;
    float bb = bias1[col];
    #pragma unroll
    for (int r=0;r<4;r++){
      float v = acc1[ct][r] + bb;
      vloc[ct][r] = v;
      sum_r[r] += v;
    }
  }
  #pragma unroll
  for (int o=1;o<16;o<<=1)
    #pragma unroll
    for (int r=0;r<4;r++) sum_r[r] += __shfl_xor(sum_r[r], o);
  if (l15 == 0){
    #pragma unroll
    for (int r=0;r<4;r++) scrA[wave][kq*4+r] = sum_r[r];
  }
  __syncthreads();                                   // all MFMA A-frag reads done
  float mu_r[4];
  #pragma unroll
  for (int r=0;r<4;r++){
    int m = kq*4+r;
    float s_ = 0.f;
    #pragma unroll
    for (int w=0;w<8;w++) s_ += scrA[w][m];
    mu_r[r] = s_*(1.f/512.f);
  }
  float q_r[4] = {0,0,0,0};
  #pragma unroll
  for (int ct=0; ct<4; ct++)
    #pragma unroll
    for (int r=0;r<4;r++){ float dd = vloc[ct][r]-mu_r[r]; q_r[r] += dd*dd; }
  #pragma unroll
  for (int o=1;o<16;o<<=1)
    #pragma unroll
    for (int r=0;r<4;r++) q_r[r] += __shfl_xor(q_r[r], o);
  if (l15 == 0){
    #pragma unroll
    for (int r=0;r<4;r++) scrB[wave][kq*4+r] = q_r[r];
  }
  __syncthreads();
  unsigned short* h1s = AggHi;                       // reuse (reads complete)
  #pragma unroll
  for (int r=0;r<4;r++){
    int m = kq*4+r;
    float vs = 0.f;
    #pragma unroll
    for (int w=0;w<8;w++) vs += scrB[w][m];
    float var = vs*(1.f/512.f);
    float rsv = rsqrtf(var+LN_EPS);
    #pragma unroll
    for (int ct=0; ct<4; ct++){
      int col = wave*64 + ct*16 + l15;
      float y = gelu_ex((vloc[ct][r]-mu_r[r])*rsv*g1[col] + b1[col]);
      h1s[(size_t)m*520 + col] = (unsigned short)f2bf(y);
    }
  }
  __syncthreads();

  // ---- Phase C: fused GEMM2 (wave covers out-cols [wave*16, +16)); K=512 ----
  f32x4 acc2 = {};
  const uint4* h1s4 = (const uint4*)h1s;
  int colc = wave*16 + l15;
  #pragma unroll
  for (int kt=0; kt<16; kt++){
    BF8 fa; fa.u4 = h1s4[(size_t)l15*65 + kt*4 + kq];
    BF8 fb; fb.u4 = *(const uint4*)&W2t[(size_t)colc*512 + kt*32 + kq*8];
    acc2 = __builtin_amdgcn_mfma_f32_16x16x32_bf16(fa.v, fb.v, acc2, 0,0,0);
  }
  float ps[4], pd[4];
  {
    float ws = att2_s[colc], wd = att2_d[colc];
    #pragma unroll
    for (int r2=0; r2<4; r2++){
      float vv = acc2[r2];
      xh2b[(size_t)(dstbase + kq*4 + r2)*128 + colc] = (unsigned short)f2bf(vv);
      ps[r2] = vv*ws; pd[r2] = vv*wd;
    }
  }
  #pragma unroll
  for (int o=1;o<16;o<<=1){
    #pragma unroll
    for (int r2=0;r2<4;r2++){ ps[r2]+=__shfl_xor(ps[r2],o); pd[r2]+=__shfl_xor(pd[r2],o); }
  }
  if (l15 == 0){
    #pragma unroll
    for (int r2=0;r2<4;r2++){
      scrS[wave][kq*4+r2] = ps[r2];
      scrD[wave][kq*4+r2] = pd[r2];
    }
  }
  __syncthreads();
  if (tid < 16){
    float ss = 0.f, sd = 0.f;
    #pragma unroll
    for (int w=0;w<8;w++){ ss += scrS[w][tid]; sd += scrD[w][tid]; }
    als2[dstbase+tid] = ss;
    ald2[dstbase+tid] = sd;
  }
}

// -- GAT layer 2: bf16 table, 4 nodes/block (wave=node); packed LDS reads;
//    r15: Wo staged in LDS (was 64 in-loop L2 dword loads per dst); __expf/__logf.
//    projection uses __shfl (ds_bpermute, per-lane index) — NOT readlane
//    (divergent lane index made the compiler waterfall it). --
__global__ __launch_bounds__(256) void k_gat2_final(
    const unsigned* __restrict__ xh,                 // [N,64] uint = [N,128] bf16
    const float* __restrict__ als, const float* __restrict__ ald, // [N]
    const int* __restrict__ cnt, const int* __restrict__ ell,
    const float* __restrict__ bias2, const float* __restrict__ g2, const float* __restrict__ b2,
    const float* __restrict__ Wo, const float* __restrict__ bo,
    float* __restrict__ out)                         // [N,32]
{
  __shared__ float WoS[128*32];                      // 16 KB staged weight
  __shared__ float alphaS[4][64];
  __shared__ int   srcS[4][64];
  {
    const float4* W4 = (const float4*)Wo;
    float4* S4 = (float4*)WoS;
    #pragma unroll
    for (int i=0;i<4;i++) S4[threadIdx.x + i*256] = W4[threadIdx.x + i*256];
  }
  __syncthreads();

  int wave = threadIdx.x>>6, t = threadIdx.x&63;
  int d = blockIdx.x*4 + wave;
  int deg = min(cnt[d], 64);
  int s0 = ell[d*64 + t];                            // unconditional; masked below
  float add = ald[d];
  s0 = (t < deg) ? s0 : 0;
  float lg = als[s0] + add;
  float ex = (t < deg) ? __expf(lrelu02(lg)) : 0.f;
  alphaS[wave][t] = ex;
  srcS[wave][t] = s0;
  float den = ex, acc0 = 0.f, acc1 = 0.f;

  int degR = (deg + 7) & ~7;
  for (int j=0; j<degR; j+=8){                       // packed LDS + 8 loads in flight
    int4 sA4 = *(const int4*)&srcS[wave][j];
    int4 sB4 = *(const int4*)&srcS[wave][j+4];
    unsigned u[8];
    u[0] = xh[(size_t)sA4.x*64 + t];
    u[1] = xh[(size_t)sA4.y*64 + t];
    u[2] = xh[(size_t)sA4.z*64 + t];
    u[3] = xh[(size_t)sA4.w*64 + t];
    u[4] = xh[(size_t)sB4.x*64 + t];
    u[5] = xh[(size_t)sB4.y*64 + t];
    u[6] = xh[(size_t)sB4.z*64 + t];
    u[7] = xh[(size_t)sB4.w*64 + t];
    float4 aA = *(const float4*)&alphaS[wave][j];
    float4 aB = *(const float4*)&alphaS[wave][j+4];
    acc0 += aA.x*bflo(u[0]); acc1 += aA.x*bfhi(u[0]);
    acc0 += aA.y*bflo(u[1]); acc1 += aA.y*bfhi(u[1]);
    acc0 += aA.z*bflo(u[2]); acc1 += aA.z*bfhi(u[2]);
    acc0 += aA.w*bflo(u[3]); acc1 += aA.w*bfhi(u[3]);
    acc0 += aB.x*bflo(u[4]); acc1 += aB.x*bfhi(u[4]);
    acc0 += aB.y*bflo(u[5]); acc1 += aB.y*bfhi(u[5]);
    acc0 += aB.z*bflo(u[6]); acc1 += aB.z*bfhi(u[6]);
    acc0 += aB.w*bflo(u[7]); acc1 += aB.w*bfhi(u[7]);
  }
  #pragma unroll
  for (int o=32;o>0;o>>=1) den += __shfl_down(den,o);
  den = __shfl(den,0);
  float inv = 1.f/den;
  float2 bb = ((const float2*)bias2)[t];
  float v0 = acc0*inv + bb.x;
  float v1 = acc1*inv + bb.y;

  // LN(128) — wave-only reductions
  float s1 = v0+v1;
  #pragma unroll
  for (int o=32;o>0;o>>=1) s1 += __shfl_down(s1,o);
  s1 = __shfl(s1,0);
  float mu = s1*(1.f/128.f);
  float d0=v0-mu, d1=v1-mu;
  float q = d0*d0+d1*d1;
  #pragma unroll
  for (int o=32;o>0;o>>=1) q += __shfl_down(q,o);
  q = __shfl(q,0);
  float rs = rsqrtf(q*(1.f/128.f)+LN_EPS);
  float2 gg = ((const float2*)g2)[t];
  float2 b4 = ((const float2*)b2)[t];
  float y0 = gelu_ex(d0*rs*gg.x+b4.x);
  float y1 = gelu_ex(d1*rs*gg.y+b4.y);

  // projection (128->32): half-wave `half` covers k in [64*half, 64*half+64)
  int half = t>>5, c = t&31;
  int kb = half*64;
  float part = 0.f;
  #pragma unroll 8
  for (int k2=0;k2<32;k2++){
    int lsrc = (kb>>1) + k2;                         // lane holding ch kb+2k2, kb+2k2+1
    float h0 = __shfl(y0, lsrc);                     // ds_bpermute: per-lane index OK
    float h1 = __shfl(y1, lsrc);
    part += h0*WoS[(kb+2*k2)*32 + c] + h1*WoS[(kb+2*k2+1)*32 + c];
  }
  part += __shfl_down(part, 32);                     // lanes 0..31 hold full dot
  float logit = part + bo[c];

  // log_softmax over 32 (lanes 0..31)
  float mx = logit;
  #pragma unroll
  for (int o=16;o>0;o>>=1) mx = fmaxf(mx, __shfl_xor(mx,o));
  float se = __expf(logit-mx);
  #pragma unroll
  for (int o=16;o>0;o>>=1) se += __shfl_xor(se,o);
  float lse = mx + __logf(se);
  if (t < 32) out[(size_t)d*32+t] = logit - lse;
}

extern "C" void kernel_launch(void* const* d_in, const int* in_sizes, int n_in,
                              void* d_out, int out_size, void* d_ws, size_t ws_size,
                              hipStream_t stream) {
  const float* x      = (const float*)d_in[0];
  const int*   ei     = (const int*)d_in[1];
  const float* g_in   = (const float*)d_in[2];
  const float* b_in   = (const float*)d_in[3];
  const float* W1     = (const float*)d_in[4];
  const float* att1_s = (const float*)d_in[5];
  const float* att1_d = (const float*)d_in[6];
  const float* bias1  = (const float*)d_in[7];
  const float* g1     = (const float*)d_in[8];
  const float* b1     = (const float*)d_in[9];
  const float* W2     = (const float*)d_in[10];
  const float* att2_s = (const float*)d_in[11];
  const float* att2_d = (const float*)d_in[12];
  const float* bias2  = (const float*)d_in[13];
  const float* g2     = (const float*)d_in[14];
  const float* b2     = (const float*)d_in[15];
  const float* Wo     = (const float*)d_in[16];
  const float* bo     = (const float*)d_in[17];
  float* out = (float*)d_out;

  char* ws = (char*)d_ws;
  size_t off = 0;
  auto alloc = [&](size_t bytes)->char*{
    char* p = ws + off; off += (bytes + 255) & ~(size_t)255; return p;
  };
  unsigned* h0b   = (unsigned*)alloc((size_t)N_NODES*128*2);       // LN(x) bf16 table
  unsigned short* xh2b = (unsigned short*)alloc((size_t)N_NODES*128*2); // fused GEMM2 out bf16
  float*    als1  = (float*)alloc((size_t)N_NODES*4*4);
  float*    ald1  = (float*)alloc((size_t)N_NODES*4*4);
  float*    als2  = (float*)alloc((size_t)N_NODES*4);
  float*    ald2  = (float*)alloc((size_t)N_NODES*4);
  int*      cnt   = (int*)alloc((size_t)N_NODES*4);
  int*      ell   = (int*)alloc((size_t)N_NODES*64*4);             // ELL adjacency
  unsigned short* W1t = (unsigned short*)alloc((size_t)512*128*2); // [512][128] bf16
  unsigned short* W2t = (unsigned short*)alloc((size_t)128*512*2); // [128][512] bf16
  float*    wtil  = (float*)alloc((size_t)8*128*4);                // fused logit vecs

  // 1. weight transposes + parallel w~ + zero cnt
  k_prep<<<TB1 + TB2 + WTB + ZCB,256,0,stream>>>(W1, W2, att1_s, att1_d,
                                                 W1t, W2t, wtil, cnt);
  // 2. ELL build + input LN + fp32 att1 logits
  k_build_mega<<<EBL + LNB,256,0,stream>>>(ei, cnt, ell, x, g_in, b_in, wtil,
                                           h0b, (float4*)als1, (float4*)ald1);
  // 3. GAT1 in input space + W1-proj MFMA + LN/GELU + fused GEMM2 + att2 logits
  k_gat1_fused<<<N_NODES/16,512,0,stream>>>(h0b,
      (const float4*)als1, (const float4*)ald1, cnt, ell,
      bias1, g1, b1, W1t, W2t, att2_s, att2_d, xh2b, als2, ald2);
  // 4. GAT layer 2 + Wo projection + log_softmax
  k_gat2_final<<<N_NODES/4,256,0,stream>>>((const unsigned*)xh2b, als2, ald2,
      cnt, ell, bias2, g2, b2, Wo, bo, out);
}

// Round 2
// 221.757 us; speedup vs baseline: 1.0110x; 1.0110x over previous
//
#include <hip/hip_runtime.h>
#include <hip/hip_bf16.h>
#include <math.h>

static constexpr int N_NODES = 20000;
static constexpr int N_EDGES = 320000;
static constexpr int ETOT    = N_EDGES + N_NODES;   // edges + self loops
static constexpr float LN_EPS = 1e-5f;

__device__ __forceinline__ float lrelu02(float x){ return x > 0.f ? x : 0.2f*x; }
__device__ __forceinline__ float gelu_ex(float x){ return 0.5f*x*(1.f+erff(x*0.70710678118654752f)); }
__device__ __forceinline__ float bflo(unsigned u){ return __uint_as_float(u<<16); }
__device__ __forceinline__ float bfhi(unsigned u){ return __uint_as_float(u & 0xffff0000u); }
__device__ __forceinline__ unsigned f2bf(float f){           // RNE fp32->bf16
  unsigned u = __float_as_uint(f);
  return (u + 0x7fffu + ((u>>16)&1u)) >> 16;
}
__device__ __forceinline__ unsigned packbf2(float a, float b){ return f2bf(a) | (f2bf(b)<<16); }

typedef __attribute__((ext_vector_type(8))) short bf16x8;
typedef __attribute__((ext_vector_type(4))) float f32x4;
union BF8 { unsigned short us[8]; bf16x8 v; uint4 u4; };

// ---- prep: weight transposes + PARALLEL w~ + zero cnt ----
static constexpr int TB1 = 512*128/256;             // 256 blocks W1t
static constexpr int TB2 = 512*128/256;             // 256 blocks W2t
static constexpr int WTB = 128;                     // 128 blocks wtil (8 outs ea, 32 thr/out)
static constexpr int ZCB = (N_NODES + 255)/256;     // 79 blocks zero-cnt
__global__ __launch_bounds__(256) void k_prep(
    const float* __restrict__ W1, const float* __restrict__ W2,
    const float* __restrict__ att1_s, const float* __restrict__ att1_d,
    unsigned short* __restrict__ W1t, unsigned short* __restrict__ W2t,
    float* __restrict__ wtil, int* __restrict__ cnt) {
  int b = blockIdx.x, tid = threadIdx.x;
  if (b < TB1){                                     // W1t[n][k]=bf16(W1[k][n]) K=128,N=512
    int idx = b*256 + tid;
    int n = idx >> 7, k = idx & 127;
    W1t[idx] = (unsigned short)f2bf(W1[(size_t)k*512 + n]);
    return;
  }
  if (b < TB1 + TB2){                               // W2t[n][k]=bf16(W2[k][n]) K=512,N=128
    int idx = (b-TB1)*256 + tid;
    int n = idx >> 9, k = idx & 511;
    W2t[idx] = (unsigned short)f2bf(W2[(size_t)k*128 + n]);
    return;
  }
  if (b < TB1 + TB2 + WTB){
    // wtil[v*128+k] = sum_c W1[k, (v&3)*128+c]*att{s|d}[(v&3),c]; 32 thr/output
    int o = (b-TB1-TB2)*8 + (tid>>5);               // 0..1023
    int c32 = tid & 31;
    int v = o >> 7, k = o & 127, h = v & 3;
    const float* av = (v < 4) ? (att1_s + h*128) : (att1_d + h*128);
    const float* wr = W1 + (size_t)k*512 + h*128;
    float p = wr[c32]*av[c32] + wr[c32+32]*av[c32+32]
            + wr[c32+64]*av[c32+64] + wr[c32+96]*av[c32+96];
    #pragma unroll
    for (int o2=1;o2<32;o2<<=1) p += __shfl_xor(p, o2);
    if (c32 == 0) wtil[o] = p;
    return;
  }
  int idx = (b - TB1 - TB2 - WTB)*256 + tid;        // zero cnt
  if (idx < N_NODES) cnt[idx] = 0;
}

// ---- mega kernel: ELL build (atomic slots) + input LN + fp32 att1 logits ----
static constexpr int EBL = (ETOT + 255)/256;        // 1329 edge blocks
static constexpr int LNB = N_NODES/4;               // 5000 LN blocks (4 rows ea)
__global__ __launch_bounds__(256) void k_build_mega(
    const int* __restrict__ ei, int* __restrict__ cnt, int* __restrict__ ell,
    const float* __restrict__ x, const float* __restrict__ g_in,
    const float* __restrict__ b_in, const float* __restrict__ wtil,
    unsigned* __restrict__ h0b, float4* __restrict__ als4, float4* __restrict__ ald4) {
  int b = blockIdx.x, tid = threadIdx.x;
  if (b < EBL){                                     // ELL scatter (deg<=64 w.h.p.)
    int e = b*256 + tid;
    int s, d;
    if (e < N_EDGES){ s = ei[e]; d = ei[N_EDGES+e]; }
    else if (e < ETOT){ s = e - N_EDGES; d = s; }
    else return;
    int pos = atomicAdd(&cnt[d], 1);
    if (pos < 64) ell[d*64 + pos] = s;
    return;
  }
  // LN over 128-ch rows -> bf16 h0b; logits als/ald = h0 . w~ (fp32 exact)
  int row = (b - EBL)*4 + (tid>>6);
  int t = tid & 63;
  float2 v = ((const float2*)(x + (size_t)row*128))[t];
  float s = v.x + v.y;
  #pragma unroll
  for (int o=32;o>0;o>>=1) s += __shfl_down(s,o);
  s = __shfl(s,0);
  float mu = s*(1.f/128.f);
  float d0 = v.x-mu, d1 = v.y-mu;
  float q = d0*d0+d1*d1;
  #pragma unroll
  for (int o=32;o>0;o>>=1) q += __shfl_down(q,o);
  q = __shfl(q,0);
  float rs = rsqrtf(q*(1.f/128.f)+LN_EPS);
  float2 gg = ((const float2*)g_in)[t];
  float2 bb = ((const float2*)b_in)[t];
  float y0 = d0*rs*gg.x+bb.x;
  float y1 = d1*rs*gg.y+bb.y;
  h0b[(size_t)row*64 + t] = packbf2(y0,y1);
  float ps[4], pd[4];
  #pragma unroll
  for (int h=0;h<4;h++){
    float2 ws = ((const float2*)(wtil + h*128))[t];
    float2 wd = ((const float2*)(wtil + (4+h)*128))[t];
    ps[h] = y0*ws.x + y1*ws.y;
    pd[h] = y0*wd.x + y1*wd.y;
  }
  #pragma unroll
  for (int o=1;o<64;o<<=1){
    #pragma unroll
    for (int h=0;h<4;h++){ ps[h]+=__shfl_xor(ps[h],o); pd[h]+=__shfl_xor(pd[h],o); }
  }
  if (t==0){
    als4[row] = make_float4(ps[0],ps[1],ps[2],ps[3]);
    ald4[row] = make_float4(pd[0],pd[1],pd[2],pd[3]);
  }
}

// ---- GAT1 in input space + W1-proj MFMA + LN/GELU + GEMM2 + att2 ----
// r16: gather unrolled to 16 slots/iter (16 loads in flight, 2x MLP) + 32-bit
// gather addressing (saddr+voffset form). 512 thr / 8 waves, 16 dst/block.
__global__ __launch_bounds__(512) void k_gat1_fused(
    const unsigned* __restrict__ h0,                 // [N][64] uint = [N,128] bf16
    const float4* __restrict__ als4, const float4* __restrict__ ald4, // [N]
    const int* __restrict__ cnt, const int* __restrict__ ell,
    const float* __restrict__ bias1, const float* __restrict__ g1, const float* __restrict__ b1,
    const unsigned short* __restrict__ W1t,          // [512][128] bf16
    const unsigned short* __restrict__ W2t,          // [128][512] bf16
    const float* __restrict__ att2_s, const float* __restrict__ att2_d, // [128]
    unsigned short* __restrict__ xh2b,               // [N,128] bf16
    float* __restrict__ als2, float* __restrict__ ald2) // [N]
{
  __shared__ unsigned short AggHi[16*520];           // reused as h1 tile later
  __shared__ float4 alphaW4[8][64];                  // 4 head-alphas packed per slot
  __shared__ int   srcW[8][64];
  __shared__ float scrA[8][16], scrB[8][16];
  __shared__ float scrS[8][16], scrD[8][16];
  int dstbase = blockIdx.x*16;
  int tid = threadIdx.x, wave = tid>>6, lane = tid&63;
  int kq = lane>>4, l15 = lane&15;

  // ---- Phase A: descriptors upfront (cheap), als4 staged 1-deep ----
  int degP[2], sP[2];
  float4 adP[2];
  #pragma unroll
  for (int r=0;r<2;r++){
    int d = dstbase + r*8 + wave;
    degP[r] = min(cnt[d],64);
    sP[r]   = ell[d*64 + lane];                      // unconditional
    adP[r]  = ald4[d];
  }
  #pragma unroll
  for (int r=0;r<2;r++) sP[r] = (lane < degP[r]) ? sP[r] : 0;
  float4 asCur = als4[sP[0]];

  unsigned* Hi = (unsigned*)AggHi;
  #pragma unroll
  for (int r=0; r<2; r++){
    float4 asNext;
    if (r < 1) asNext = als4[sP[1]];                 // in flight during this round
    int row = r*8 + wave;                            // 0..15
    int deg = degP[r];
    float4 ad_ = adP[r];
    float e0=0.f,e1=0.f,e2=0.f,e3=0.f;
    if (lane < deg){
      e0 = __expf(lrelu02(asCur.x+ad_.x));
      e1 = __expf(lrelu02(asCur.y+ad_.y));
      e2 = __expf(lrelu02(asCur.z+ad_.z));
      e3 = __expf(lrelu02(asCur.w+ad_.w));
    }
    srcW[wave][lane] = sP[r];
    alphaW4[wave][lane] = make_float4(e0,e1,e2,e3);
    float q0=e0,q1=e1,q2=e2,q3=e3;
    #pragma unroll
    for (int o=1;o<64;o<<=1){
      q0+=__shfl_xor(q0,o); q1+=__shfl_xor(q1,o);
      q2+=__shfl_xor(q2,o); q3+=__shfl_xor(q3,o);
    }
    float inv[4] = {1.f/q0, 1.f/q1, 1.f/q2, 1.f/q3};

    float acc[8] = {};                               // [head*2 + (lo,hi)]
    int degR = (deg + 15) & ~15;
    for (int j=0; j<degR; j+=16){                    // 16 loads in flight (2x MLP)
      int4 sA4 = *(const int4*)&srcW[wave][j];       // packed src reads
      int4 sB4 = *(const int4*)&srcW[wave][j+4];
      int4 sC4 = *(const int4*)&srcW[wave][j+8];
      int4 sD4 = *(const int4*)&srcW[wave][j+12];
      unsigned v[16];
      v[ 0] = h0[(unsigned)sA4.x*64u + lane];
      v[ 1] = h0[(unsigned)sA4.y*64u + lane];
      v[ 2] = h0[(unsigned)sA4.z*64u + lane];
      v[ 3] = h0[(unsigned)sA4.w*64u + lane];
      v[ 4] = h0[(unsigned)sB4.x*64u + lane];
      v[ 5] = h0[(unsigned)sB4.y*64u + lane];
      v[ 6] = h0[(unsigned)sB4.z*64u + lane];
      v[ 7] = h0[(unsigned)sB4.w*64u + lane];
      v[ 8] = h0[(unsigned)sC4.x*64u + lane];
      v[ 9] = h0[(unsigned)sC4.y*64u + lane];
      v[10] = h0[(unsigned)sC4.z*64u + lane];
      v[11] = h0[(unsigned)sC4.w*64u + lane];
      v[12] = h0[(unsigned)sD4.x*64u + lane];
      v[13] = h0[(unsigned)sD4.y*64u + lane];
      v[14] = h0[(unsigned)sD4.z*64u + lane];
      v[15] = h0[(unsigned)sD4.w*64u + lane];
      #pragma unroll
      for (int i=0;i<16;i++){
        float4 a = alphaW4[wave][j+i];               // ONE b128 broadcast/edge
        float lo = bflo(v[i]), hi = bfhi(v[i]);
        acc[0]+=a.x*lo; acc[1]+=a.x*hi;
        acc[2]+=a.y*lo; acc[3]+=a.y*hi;
        acc[4]+=a.z*lo; acc[5]+=a.z*hi;
        acc[6]+=a.w*lo; acc[7]+=a.w*hi;
      }
    }
    // normalize; lane owns ch pair (2*lane, 2*lane+1) per head; bf16 pack
    #pragma unroll
    for (int h=0; h<4; h++){
      float x0 = acc[2*h]*inv[h], x1 = acc[2*h+1]*inv[h];
      Hi[row*260 + h*64 + lane] = packbf2(x0,x1);
    }
    if (r < 1) asCur = asNext;
  }
  __syncthreads();

  // ---- Phase B: W1 projection; wave covers cols [wave*64, wave*64+64), head = wave>>1 ----
  f32x4 acc1[4] = {};
  {
    const uint4* Hi4 = (const uint4*)AggHi;
    int h = wave>>1;
    #pragma unroll
    for (int kt=0; kt<4; kt++){
      BF8 fh;
      fh.u4 = Hi4[(size_t)l15*65 + h*16 + kt*4 + kq];
      #pragma unroll
      for (int ct=0; ct<4; ct++){
        int col = wave*64 + ct*16 + l15;
        BF8 fb; fb.u4 = *(const uint4*)&W1t[(size_t)col*128 + kt*32 + kq*8];
        acc1[ct] = __builtin_amdgcn_mfma_f32_16x16x32_bf16(fh.v, fb.v, acc1[ct], 0,0,0);
      }
    }
  }
  // epilogue: bias + LN(512) + GELU; C layout: m = kq*4+r, col = wave*64+ct*16+l15
  float vloc[4][4];
  float sum_r[4] = {0,0,0,0};
  #pragma unroll
  for (int ct=0; ct<4; ct++){
    int col = wave*64 + ct*16 + l15;
    float bb = bias1[col];
    #pragma unroll
    for (int r=0;r<4;r++){
      float v = acc1[ct][r] + bb;
      vloc[ct][r] = v;
      sum_r[r] += v;
    }
  }
  #pragma unroll
  for (int o=1;o<16;o<<=1)
    #pragma unroll
    for (int r=0;r<4;r++) sum_r[r] += __shfl_xor(sum_r[r], o);
  if (l15 == 0){
    #pragma unroll
    for (int r=0;r<4;r++) scrA[wave][kq*4+r] = sum_r[r];
  }
  __syncthreads();                                   // all MFMA A-frag reads done
  float mu_r[4];
  #pragma unroll
  for (int r=0;r<4;r++){
    int m = kq*4+r;
    float s_ = 0.f;
    #pragma unroll
    for (int w=0;w<8;w++) s_ += scrA[w][m];
    mu_r[r] = s_*(1.f/512.f);
  }
  float q_r[4] = {0,0,0,0};
  #pragma unroll
  for (int ct=0; ct<4; ct++)
    #pragma unroll
    for (int r=0;r<4;r++){ float dd = vloc[ct][r]-mu_r[r]; q_r[r] += dd*dd; }
  #pragma unroll
  for (int o=1;o<16;o<<=1)
    #pragma unroll
    for (int r=0;r<4;r++) q_r[r] += __shfl_xor(q_r[r], o);
  if (l15 == 0){
    #pragma unroll
    for (int r=0;r<4;r++) scrB[wave][kq*4+r] = q_r[r];
  }
  __syncthreads();
  unsigned short* h1s = AggHi;                       // reuse (reads complete)
  #pragma unroll
  for (int r=0;r<4;r++){
    int m = kq*4+r;
    float vs = 0.f;
    #pragma unroll
    for (int w=0;w<8;w++) vs += scrB[w][m];
    float var = vs*(1.f/512.f);
    float rsv = rsqrtf(var+LN_EPS);
    #pragma unroll
    for (int ct=0; ct<4; ct++){
      int col = wave*64 + ct*16 + l15;
      float y = gelu_ex((vloc[ct][r]-mu_r[r])*rsv*g1[col] + b1[col]);
      h1s[(size_t)m*520 + col] = (unsigned short)f2bf(y);
    }
  }
  __syncthreads();

  // ---- Phase C: fused GEMM2 (wave covers out-cols [wave*16, +16)); K=512 ----
  f32x4 acc2 = {};
  const uint4* h1s4 = (const uint4*)h1s;
  int colc = wave*16 + l15;
  #pragma unroll
  for (int kt=0; kt<16; kt++){
    BF8 fa; fa.u4 = h1s4[(size_t)l15*65 + kt*4 + kq];
    BF8 fb; fb.u4 = *(const uint4*)&W2t[(size_t)colc*512 + kt*32 + kq*8];
    acc2 = __builtin_amdgcn_mfma_f32_16x16x32_bf16(fa.v, fb.v, acc2, 0,0,0);
  }
  float ps[4], pd[4];
  {
    float ws = att2_s[colc], wd = att2_d[colc];
    #pragma unroll
    for (int r2=0; r2<4; r2++){
      float vv = acc2[r2];
      xh2b[(size_t)(dstbase + kq*4 + r2)*128 + colc] = (unsigned short)f2bf(vv);
      ps[r2] = vv*ws; pd[r2] = vv*wd;
    }
  }
  #pragma unroll
  for (int o=1;o<16;o<<=1){
    #pragma unroll
    for (int r2=0;r2<4;r2++){ ps[r2]+=__shfl_xor(ps[r2],o); pd[r2]+=__shfl_xor(pd[r2],o); }
  }
  if (l15 == 0){
    #pragma unroll
    for (int r2=0;r2<4;r2++){
      scrS[wave][kq*4+r2] = ps[r2];
      scrD[wave][kq*4+r2] = pd[r2];
    }
  }
  __syncthreads();
  if (tid < 16){
    float ss = 0.f, sd = 0.f;
    #pragma unroll
    for (int w=0;w<8;w++){ ss += scrS[w][tid]; sd += scrD[w][tid]; }
    als2[dstbase+tid] = ss;
    ald2[dstbase+tid] = sd;
  }
}

// -- GAT layer 2: bf16 table, 4 nodes/block (wave=node); packed LDS reads;
//    r16: Wo LDS staging REVERTED (Wo is 16KB = L1-resident; staging added 80MB
//    L2 traffic + a barrier and regressed ~7us). Gather unrolled to 16 slots
//    (2x MLP) + 32-bit addressing. __expf/__logf kept (absmax unchanged). --
__global__ __launch_bounds__(256) void k_gat2_final(
    const unsigned* __restrict__ xh,                 // [N,64] uint = [N,128] bf16
    const float* __restrict__ als, const float* __restrict__ ald, // [N]
    const int* __restrict__ cnt, const int* __restrict__ ell,
    const float* __restrict__ bias2, const float* __restrict__ g2, const float* __restrict__ b2,
    const float* __restrict__ Wo, const float* __restrict__ bo,
    float* __restrict__ out)                         // [N,32]
{
  int wave = threadIdx.x>>6, t = threadIdx.x&63;
  int d = blockIdx.x*4 + wave;
  __shared__ float alphaS[4][64];
  __shared__ int   srcS[4][64];
  int deg = min(cnt[d], 64);
  int s0 = ell[d*64 + t];                            // unconditional; masked below
  float add = ald[d];
  s0 = (t < deg) ? s0 : 0;
  float lg = als[s0] + add;
  float ex = (t < deg) ? __expf(lrelu02(lg)) : 0.f;
  alphaS[wave][t] = ex;
  srcS[wave][t] = s0;
  float den = ex, acc0 = 0.f, acc1 = 0.f;

  int degR = (deg + 15) & ~15;
  for (int j=0; j<degR; j+=16){                      // 16 loads in flight (2x MLP)
    int4 sA4 = *(const int4*)&srcS[wave][j];
    int4 sB4 = *(const int4*)&srcS[wave][j+4];
    int4 sC4 = *(const int4*)&srcS[wave][j+8];
    int4 sD4 = *(const int4*)&srcS[wave][j+12];
    unsigned u[16];
    u[ 0] = xh[(unsigned)sA4.x*64u + t];
    u[ 1] = xh[(unsigned)sA4.y*64u + t];
    u[ 2] = xh[(unsigned)sA4.z*64u + t];
    u[ 3] = xh[(unsigned)sA4.w*64u + t];
    u[ 4] = xh[(unsigned)sB4.x*64u + t];
    u[ 5] = xh[(unsigned)sB4.y*64u + t];
    u[ 6] = xh[(unsigned)sB4.z*64u + t];
    u[ 7] = xh[(unsigned)sB4.w*64u + t];
    u[ 8] = xh[(unsigned)sC4.x*64u + t];
    u[ 9] = xh[(unsigned)sC4.y*64u + t];
    u[10] = xh[(unsigned)sC4.z*64u + t];
    u[11] = xh[(unsigned)sC4.w*64u + t];
    u[12] = xh[(unsigned)sD4.x*64u + t];
    u[13] = xh[(unsigned)sD4.y*64u + t];
    u[14] = xh[(unsigned)sD4.z*64u + t];
    u[15] = xh[(unsigned)sD4.w*64u + t];
    float4 aA = *(const float4*)&alphaS[wave][j];
    float4 aB = *(const float4*)&alphaS[wave][j+4];
    float4 aC = *(const float4*)&alphaS[wave][j+8];
    float4 aD = *(const float4*)&alphaS[wave][j+12];
    acc0 += aA.x*bflo(u[ 0]); acc1 += aA.x*bfhi(u[ 0]);
    acc0 += aA.y*bflo(u[ 1]); acc1 += aA.y*bfhi(u[ 1]);
    acc0 += aA.z*bflo(u[ 2]); acc1 += aA.z*bfhi(u[ 2]);
    acc0 += aA.w*bflo(u[ 3]); acc1 += aA.w*bfhi(u[ 3]);
    acc0 += aB.x*bflo(u[ 4]); acc1 += aB.x*bfhi(u[ 4]);
    acc0 += aB.y*bflo(u[ 5]); acc1 += aB.y*bfhi(u[ 5]);
    acc0 += aB.z*bflo(u[ 6]); acc1 += aB.z*bfhi(u[ 6]);
    acc0 += aB.w*bflo(u[ 7]); acc1 += aB.w*bfhi(u[ 7]);
    acc0 += aC.x*bflo(u[ 8]); acc1 += aC.x*bfhi(u[ 8]);
    acc0 += aC.y*bflo(u[ 9]); acc1 += aC.y*bfhi(u[ 9]);
    acc0 += aC.z*bflo(u[10]); acc1 += aC.z*bfhi(u[10]);
    acc0 += aC.w*bflo(u[11]); acc1 += aC.w*bfhi(u[11]);
    acc0 += aD.x*bflo(u[12]); acc1 += aD.x*bfhi(u[12]);
    acc0 += aD.y*bflo(u[13]); acc1 += aD.y*bfhi(u[13]);
    acc0 += aD.z*bflo(u[14]); acc1 += aD.z*bfhi(u[14]);
    acc0 += aD.w*bflo(u[15]); acc1 += aD.w*bfhi(u[15]);
  }
  #pragma unroll
  for (int o=32;o>0;o>>=1) den += __shfl_down(den,o);
  den = __shfl(den,0);
  float inv = 1.f/den;
  float2 bb = ((const float2*)bias2)[t];
  float v0 = acc0*inv + bb.x;
  float v1 = acc1*inv + bb.y;

  // LN(128) — wave-only reductions
  float s1 = v0+v1;
  #pragma unroll
  for (int o=32;o>0;o>>=1) s1 += __shfl_down(s1,o);
  s1 = __shfl(s1,0);
  float mu = s1*(1.f/128.f);
  float d0=v0-mu, d1=v1-mu;
  float q = d0*d0+d1*d1;
  #pragma unroll
  for (int o=32;o>0;o>>=1) q += __shfl_down(q,o);
  q = __shfl(q,0);
  float rs = rsqrtf(q*(1.f/128.f)+LN_EPS);
  float2 gg = ((const float2*)g2)[t];
  float2 b4 = ((const float2*)b2)[t];
  float y0 = gelu_ex(d0*rs*gg.x+b4.x);
  float y1 = gelu_ex(d1*rs*gg.y+b4.y);

  // projection (128->32): half-wave `half` covers k in [64*half, 64*half+64)
  int half = t>>5, c = t&31;
  int kb = half*64;
  float part = 0.f;
  #pragma unroll 8
  for (int k2=0;k2<32;k2++){
    int lsrc = (kb>>1) + k2;                         // lane holding ch kb+2k2, kb+2k2+1
    float h0 = __shfl(y0, lsrc);                     // ds_bpermute: per-lane index OK
    float h1 = __shfl(y1, lsrc);
    part += h0*Wo[(size_t)(kb+2*k2)*32 + c] + h1*Wo[(size_t)(kb+2*k2+1)*32 + c];
  }
  part += __shfl_down(part, 32);                     // lanes 0..31 hold full dot
  float logit = part + bo[c];

  // log_softmax over 32 (lanes 0..31)
  float mx = logit;
  #pragma unroll
  for (int o=16;o>0;o>>=1) mx = fmaxf(mx, __shfl_xor(mx,o));
  float se = __expf(logit-mx);
  #pragma unroll
  for (int o=16;o>0;o>>=1) se += __shfl_xor(se,o);
  float lse = mx + __logf(se);
  if (t < 32) out[(size_t)d*32+t] = logit - lse;
}

extern "C" void kernel_launch(void* const* d_in, const int* in_sizes, int n_in,
                              void* d_out, int out_size, void* d_ws, size_t ws_size,
                              hipStream_t stream) {
  const float* x      = (const float*)d_in[0];
  const int*   ei     = (const int*)d_in[1];
  const float* g_in   = (const float*)d_in[2];
  const float* b_in   = (const float*)d_in[3];
  const float* W1     = (const float*)d_in[4];
  const float* att1_s = (const float*)d_in[5];
  const float* att1_d = (const float*)d_in[6];
  const float* bias1  = (const float*)d_in[7];
  const float* g1     = (const float*)d_in[8];
  const float* b1     = (const float*)d_in[9];
  const float* W2     = (const float*)d_in[10];
  const float* att2_s = (const float*)d_in[11];
  const float* att2_d = (const float*)d_in[12];
  const float* bias2  = (const float*)d_in[13];
  const float* g2     = (const float*)d_in[14];
  const float* b2     = (const float*)d_in[15];
  const float* Wo     = (const float*)d_in[16];
  const float* bo     = (const float*)d_in[17];
  float* out = (float*)d_out;

  char* ws = (char*)d_ws;
  size_t off = 0;
  auto alloc = [&](size_t bytes)->char*{
    char* p = ws + off; off += (bytes + 255) & ~(size_t)255; return p;
  };
  unsigned* h0b   = (unsigned*)alloc((size_t)N_NODES*128*2);       // LN(x) bf16 table
  unsigned short* xh2b = (unsigned short*)alloc((size_t)N_NODES*128*2); // fused GEMM2 out bf16
  float*    als1  = (float*)alloc((size_t)N_NODES*4*4);
  float*    ald1  = (float*)alloc((size_t)N_NODES*4*4);
  float*    als2  = (float*)alloc((size_t)N_NODES*4);
  float*    ald2  = (float*)alloc((size_t)N_NODES*4);
  int*      cnt   = (int*)alloc((size_t)N_NODES*4);
  int*      ell   = (int*)alloc((size_t)N_NODES*64*4);             // ELL adjacency
  unsigned short* W1t = (unsigned short*)alloc((size_t)512*128*2); // [512][128] bf16
  unsigned short* W2t = (unsigned short*)alloc((size_t)128*512*2); // [128][512] bf16
  float*    wtil  = (float*)alloc((size_t)8*128*4);                // fused logit vecs

  // 1. weight transposes + parallel w~ + zero cnt
  k_prep<<<TB1 + TB2 + WTB + ZCB,256,0,stream>>>(W1, W2, att1_s, att1_d,
                                                 W1t, W2t, wtil, cnt);
  // 2. ELL build + input LN + fp32 att1 logits
  k_build_mega<<<EBL + LNB,256,0,stream>>>(ei, cnt, ell, x, g_in, b_in, wtil,
                                           h0b, (float4*)als1, (float4*)ald1);
  // 3. GAT1 in input space + W1-proj MFMA + LN/GELU + fused GEMM2 + att2 logits
  k_gat1_fused<<<N_NODES/16,512,0,stream>>>(h0b,
      (const float4*)als1, (const float4*)ald1, cnt, ell,
      bias1, g1, b1, W1t, W2t, att2_s, att2_d, xh2b, als2, ald2);
  // 4. GAT layer 2 + Wo projection + log_softmax
  k_gat2_final<<<N_NODES/4,256,0,stream>>>((const unsigned*)xh2b, als2, ald2,
      cnt, ell, bias2, g2, b2, Wo, bo, out);
}

// Round 3
// 215.973 us; speedup vs baseline: 1.0381x; 1.0268x over previous
//
#include <hip/hip_runtime.h>
#include <hip/hip_bf16.h>
#include <math.h>

static constexpr int N_NODES = 20000;
static constexpr int N_EDGES = 320000;
static constexpr int ETOT    = N_EDGES + N_NODES;   // edges + self loops
static constexpr float LN_EPS = 1e-5f;

__device__ __forceinline__ float lrelu02(float x){ return x > 0.f ? x : 0.2f*x; }
__device__ __forceinline__ float gelu_ex(float x){ return 0.5f*x*(1.f+erff(x*0.70710678118654752f)); }
__device__ __forceinline__ float bflo(unsigned u){ return __uint_as_float(u<<16); }
__device__ __forceinline__ float bfhi(unsigned u){ return __uint_as_float(u & 0xffff0000u); }
__device__ __forceinline__ unsigned f2bf(float f){           // RNE fp32->bf16
  unsigned u = __float_as_uint(f);
  return (u + 0x7fffu + ((u>>16)&1u)) >> 16;
}
__device__ __forceinline__ unsigned packbf2(float a, float b){ return f2bf(a) | (f2bf(b)<<16); }

typedef __attribute__((ext_vector_type(8))) short bf16x8;
typedef __attribute__((ext_vector_type(4))) float f32x4;
union BF8 { unsigned short us[8]; bf16x8 v; uint4 u4; };

// ---- prep: weight transposes + PARALLEL w~ + zero cnt ----
static constexpr int TB1 = 512*128/256;             // 256 blocks W1t
static constexpr int TB2 = 512*128/256;             // 256 blocks W2t
static constexpr int WTB = 128;                     // 128 blocks wtil (8 outs ea, 32 thr/out)
static constexpr int ZCB = (N_NODES + 255)/256;     // 79 blocks zero-cnt
__global__ __launch_bounds__(256) void k_prep(
    const float* __restrict__ W1, const float* __restrict__ W2,
    const float* __restrict__ att1_s, const float* __restrict__ att1_d,
    unsigned short* __restrict__ W1t, unsigned short* __restrict__ W2t,
    float* __restrict__ wtil, int* __restrict__ cnt) {
  int b = blockIdx.x, tid = threadIdx.x;
  if (b < TB1){                                     // W1t[n][k]=bf16(W1[k][n]) K=128,N=512
    int idx = b*256 + tid;
    int n = idx >> 7, k = idx & 127;
    W1t[idx] = (unsigned short)f2bf(W1[(size_t)k*512 + n]);
    return;
  }
  if (b < TB1 + TB2){                               // W2t[n][k]=bf16(W2[k][n]) K=512,N=128
    int idx = (b-TB1)*256 + tid;
    int n = idx >> 9, k = idx & 511;
    W2t[idx] = (unsigned short)f2bf(W2[(size_t)k*128 + n]);
    return;
  }
  if (b < TB1 + TB2 + WTB){
    // wtil[v*128+k] = sum_c W1[k, (v&3)*128+c]*att{s|d}[(v&3),c]; 32 thr/output
    int o = (b-TB1-TB2)*8 + (tid>>5);               // 0..1023
    int c32 = tid & 31;
    int v = o >> 7, k = o & 127, h = v & 3;
    const float* av = (v < 4) ? (att1_s + h*128) : (att1_d + h*128);
    const float* wr = W1 + (size_t)k*512 + h*128;
    float p = wr[c32]*av[c32] + wr[c32+32]*av[c32+32]
            + wr[c32+64]*av[c32+64] + wr[c32+96]*av[c32+96];
    #pragma unroll
    for (int o2=1;o2<32;o2<<=1) p += __shfl_xor(p, o2);
    if (c32 == 0) wtil[o] = p;
    return;
  }
  int idx = (b - TB1 - TB2 - WTB)*256 + tid;        // zero cnt
  if (idx < N_NODES) cnt[idx] = 0;
}

// ---- mega kernel: ELL build (atomic slots) + input LN + fp32 att1 logits ----
// r17: LN mean/var trees merged into one (Sv, Sv2) tree.
static constexpr int EBL = (ETOT + 255)/256;        // 1329 edge blocks
static constexpr int LNB = N_NODES/4;               // 5000 LN blocks (4 rows ea)
__global__ __launch_bounds__(256) void k_build_mega(
    const int* __restrict__ ei, int* __restrict__ cnt, int* __restrict__ ell,
    const float* __restrict__ x, const float* __restrict__ g_in,
    const float* __restrict__ b_in, const float* __restrict__ wtil,
    unsigned* __restrict__ h0b, float4* __restrict__ als4, float4* __restrict__ ald4) {
  int b = blockIdx.x, tid = threadIdx.x;
  if (b < EBL){                                     // ELL scatter (deg<=64 w.h.p.)
    int e = b*256 + tid;
    int s, d;
    if (e < N_EDGES){ s = ei[e]; d = ei[N_EDGES+e]; }
    else if (e < ETOT){ s = e - N_EDGES; d = s; }
    else return;
    int pos = atomicAdd(&cnt[d], 1);
    if (pos < 64) ell[d*64 + pos] = s;
    return;
  }
  // LN over 128-ch rows -> bf16 h0b; logits als/ald = h0 . w~ (fp32 exact)
  int row = (b - EBL)*4 + (tid>>6);
  int t = tid & 63;
  float2 v = ((const float2*)(x + (size_t)row*128))[t];
  float s = v.x + v.y;
  float q = v.x*v.x + v.y*v.y;
  #pragma unroll
  for (int o=32;o>0;o>>=1){ s += __shfl_down(s,o); q += __shfl_down(q,o); }
  s = __shfl(s,0); q = __shfl(q,0);
  float mu = s*(1.f/128.f);
  float var = q*(1.f/128.f) - mu*mu;
  float rs = rsqrtf(var+LN_EPS);
  float d0 = v.x-mu, d1 = v.y-mu;
  float2 gg = ((const float2*)g_in)[t];
  float2 bb = ((const float2*)b_in)[t];
  float y0 = d0*rs*gg.x+bb.x;
  float y1 = d1*rs*gg.y+bb.y;
  h0b[(size_t)row*64 + t] = packbf2(y0,y1);
  float ps[4], pd[4];
  #pragma unroll
  for (int h=0;h<4;h++){
    float2 ws = ((const float2*)(wtil + h*128))[t];
    float2 wd = ((const float2*)(wtil + (4+h)*128))[t];
    ps[h] = y0*ws.x + y1*ws.y;
    pd[h] = y0*wd.x + y1*wd.y;
  }
  #pragma unroll
  for (int o=1;o<64;o<<=1){
    #pragma unroll
    for (int h=0;h<4;h++){ ps[h]+=__shfl_xor(ps[h],o); pd[h]+=__shfl_xor(pd[h],o); }
  }
  if (t==0){
    als4[row] = make_float4(ps[0],ps[1],ps[2],ps[3]);
    ald4[row] = make_float4(pd[0],pd[1],pd[2],pd[3]);
  }
}

// ---- GAT1 in input space + W1-proj MFMA + LN/GELU + GEMM2 + att2 ----
// r17: gather back to 8 slots/iter (16-deep added waste FMAs: avg deg~17 ->
// degR jumped 24->32; r2 regressed 75.4->78.2). 32-bit addressing kept.
// LN(512) epilogue: single (Sv,Sv2) reduction -> one barrier fewer.
__global__ __launch_bounds__(512) void k_gat1_fused(
    const unsigned* __restrict__ h0,                 // [N][64] uint = [N,128] bf16
    const float4* __restrict__ als4, const float4* __restrict__ ald4, // [N]
    const int* __restrict__ cnt, const int* __restrict__ ell,
    const float* __restrict__ bias1, const float* __restrict__ g1, const float* __restrict__ b1,
    const unsigned short* __restrict__ W1t,          // [512][128] bf16
    const unsigned short* __restrict__ W2t,          // [128][512] bf16
    const float* __restrict__ att2_s, const float* __restrict__ att2_d, // [128]
    unsigned short* __restrict__ xh2b,               // [N,128] bf16
    float* __restrict__ als2, float* __restrict__ ald2) // [N]
{
  __shared__ unsigned short AggHi[16*520];           // reused as h1 tile later
  __shared__ float4 alphaW4[8][64];                  // 4 head-alphas packed per slot
  __shared__ int   srcW[8][64];
  __shared__ float scrA[8][16], scrB[8][16];
  __shared__ float scrS[8][16], scrD[8][16];
  int dstbase = blockIdx.x*16;
  int tid = threadIdx.x, wave = tid>>6, lane = tid&63;
  int kq = lane>>4, l15 = lane&15;

  // ---- Phase A: descriptors upfront (cheap), als4 staged 1-deep ----
  int degP[2], sP[2];
  float4 adP[2];
  #pragma unroll
  for (int r=0;r<2;r++){
    int d = dstbase + r*8 + wave;
    degP[r] = min(cnt[d],64);
    sP[r]   = ell[d*64 + lane];                      // unconditional
    adP[r]  = ald4[d];
  }
  #pragma unroll
  for (int r=0;r<2;r++) sP[r] = (lane < degP[r]) ? sP[r] : 0;
  float4 asCur = als4[sP[0]];

  unsigned* Hi = (unsigned*)AggHi;
  #pragma unroll
  for (int r=0; r<2; r++){
    float4 asNext;
    if (r < 1) asNext = als4[sP[1]];                 // in flight during this round
    int row = r*8 + wave;                            // 0..15
    int deg = degP[r];
    float4 ad_ = adP[r];
    float e0=0.f,e1=0.f,e2=0.f,e3=0.f;
    if (lane < deg){
      e0 = __expf(lrelu02(asCur.x+ad_.x));
      e1 = __expf(lrelu02(asCur.y+ad_.y));
      e2 = __expf(lrelu02(asCur.z+ad_.z));
      e3 = __expf(lrelu02(asCur.w+ad_.w));
    }
    srcW[wave][lane] = sP[r];
    alphaW4[wave][lane] = make_float4(e0,e1,e2,e3);
    float q0=e0,q1=e1,q2=e2,q3=e3;
    #pragma unroll
    for (int o=1;o<64;o<<=1){
      q0+=__shfl_xor(q0,o); q1+=__shfl_xor(q1,o);
      q2+=__shfl_xor(q2,o); q3+=__shfl_xor(q3,o);
    }
    float inv[4] = {1.f/q0, 1.f/q1, 1.f/q2, 1.f/q3};

    float acc[8] = {};                               // [head*2 + (lo,hi)]
    int degR = (deg + 7) & ~7;
    for (int j=0; j<degR; j+=8){                     // 8 loads in flight
      int4 sA4 = *(const int4*)&srcW[wave][j];       // packed src reads
      int4 sB4 = *(const int4*)&srcW[wave][j+4];
      unsigned v[8];
      v[0] = h0[(unsigned)sA4.x*64u + lane];
      v[1] = h0[(unsigned)sA4.y*64u + lane];
      v[2] = h0[(unsigned)sA4.z*64u + lane];
      v[3] = h0[(unsigned)sA4.w*64u + lane];
      v[4] = h0[(unsigned)sB4.x*64u + lane];
      v[5] = h0[(unsigned)sB4.y*64u + lane];
      v[6] = h0[(unsigned)sB4.z*64u + lane];
      v[7] = h0[(unsigned)sB4.w*64u + lane];
      #pragma unroll
      for (int i=0;i<8;i++){
        float4 a = alphaW4[wave][j+i];               // ONE b128 broadcast/edge
        float lo = bflo(v[i]), hi = bfhi(v[i]);
        acc[0]+=a.x*lo; acc[1]+=a.x*hi;
        acc[2]+=a.y*lo; acc[3]+=a.y*hi;
        acc[4]+=a.z*lo; acc[5]+=a.z*hi;
        acc[6]+=a.w*lo; acc[7]+=a.w*hi;
      }
    }
    // normalize; lane owns ch pair (2*lane, 2*lane+1) per head; bf16 pack
    #pragma unroll
    for (int h=0; h<4; h++){
      float x0 = acc[2*h]*inv[h], x1 = acc[2*h+1]*inv[h];
      Hi[row*260 + h*64 + lane] = packbf2(x0,x1);
    }
    if (r < 1) asCur = asNext;
  }
  __syncthreads();

  // ---- Phase B: W1 projection; wave covers cols [wave*64, wave*64+64), head = wave>>1 ----
  f32x4 acc1[4] = {};
  {
    const uint4* Hi4 = (const uint4*)AggHi;
    int h = wave>>1;
    #pragma unroll
    for (int kt=0; kt<4; kt++){
      BF8 fh;
      fh.u4 = Hi4[(size_t)l15*65 + h*16 + kt*4 + kq];
      #pragma unroll
      for (int ct=0; ct<4; ct++){
        int col = wave*64 + ct*16 + l15;
        BF8 fb; fb.u4 = *(const uint4*)&W1t[(size_t)col*128 + kt*32 + kq*8];
        acc1[ct] = __builtin_amdgcn_mfma_f32_16x16x32_bf16(fh.v, fb.v, acc1[ct], 0,0,0);
      }
    }
  }
  // epilogue: bias + LN(512) + GELU; C layout: m = kq*4+r, col = wave*64+ct*16+l15
  // r17: single-pass sum+sumsq -> ONE barrier (var = E[v^2]-mu^2)
  float vloc[4][4];
  float sum_r[4] = {0,0,0,0}, sq_r[4] = {0,0,0,0};
  #pragma unroll
  for (int ct=0; ct<4; ct++){
    int col = wave*64 + ct*16 + l15;
    float bb = bias1[col];
    #pragma unroll
    for (int r=0;r<4;r++){
      float v = acc1[ct][r] + bb;
      vloc[ct][r] = v;
      sum_r[r] += v;
      sq_r[r]  += v*v;
    }
  }
  #pragma unroll
  for (int o=1;o<16;o<<=1)
    #pragma unroll
    for (int r=0;r<4;r++){ sum_r[r] += __shfl_xor(sum_r[r], o); sq_r[r] += __shfl_xor(sq_r[r], o); }
  if (l15 == 0){
    #pragma unroll
    for (int r=0;r<4;r++){ scrA[wave][kq*4+r] = sum_r[r]; scrB[wave][kq*4+r] = sq_r[r]; }
  }
  __syncthreads();                                   // also: all MFMA A-frag reads done
  unsigned short* h1s = AggHi;                       // reuse (reads complete)
  #pragma unroll
  for (int r=0;r<4;r++){
    int m = kq*4+r;
    float s_ = 0.f, vs = 0.f;
    #pragma unroll
    for (int w=0;w<8;w++){ s_ += scrA[w][m]; vs += scrB[w][m]; }
    float mu = s_*(1.f/512.f);
    float var = vs*(1.f/512.f) - mu*mu;
    float rsv = rsqrtf(var+LN_EPS);
    #pragma unroll
    for (int ct=0; ct<4; ct++){
      int col = wave*64 + ct*16 + l15;
      float y = gelu_ex((vloc[ct][r]-mu)*rsv*g1[col] + b1[col]);
      h1s[(size_t)m*520 + col] = (unsigned short)f2bf(y);
    }
  }
  __syncthreads();

  // ---- Phase C: fused GEMM2 (wave covers out-cols [wave*16, +16)); K=512 ----
  f32x4 acc2 = {};
  const uint4* h1s4 = (const uint4*)h1s;
  int colc = wave*16 + l15;
  #pragma unroll
  for (int kt=0; kt<16; kt++){
    BF8 fa; fa.u4 = h1s4[(size_t)l15*65 + kt*4 + kq];
    BF8 fb; fb.u4 = *(const uint4*)&W2t[(size_t)colc*512 + kt*32 + kq*8];
    acc2 = __builtin_amdgcn_mfma_f32_16x16x32_bf16(fa.v, fb.v, acc2, 0,0,0);
  }
  float ps[4], pd[4];
  {
    float ws = att2_s[colc], wd = att2_d[colc];
    #pragma unroll
    for (int r2=0; r2<4; r2++){
      float vv = acc2[r2];
      xh2b[(size_t)(dstbase + kq*4 + r2)*128 + colc] = (unsigned short)f2bf(vv);
      ps[r2] = vv*ws; pd[r2] = vv*wd;
    }
  }
  #pragma unroll
  for (int o=1;o<16;o<<=1){
    #pragma unroll
    for (int r2=0;r2<4;r2++){ ps[r2]+=__shfl_xor(ps[r2],o); pd[r2]+=__shfl_xor(pd[r2],o); }
  }
  if (l15 == 0){
    #pragma unroll
    for (int r2=0;r2<4;r2++){
      scrS[wave][kq*4+r2] = ps[r2];
      scrD[wave][kq*4+r2] = pd[r2];
    }
  }
  __syncthreads();
  if (tid < 16){
    float ss = 0.f, sd = 0.f;
    #pragma unroll
    for (int w=0;w<8;w++){ ss += scrS[w][tid]; sd += scrD[w][tid]; }
    als2[dstbase+tid] = ss;
    ald2[dstbase+tid] = sd;
  }
}

// -- GAT layer 2: bf16 table, 4 nodes/block (wave=node); packed LDS reads;
//    r17: gather back to 8/iter; projection via LDS broadcast reads (16
//    ds_read_b128 replaces 64 ds_bpermute); LN mean/var trees merged.
//    Wo direct loads (16KB = L1-resident; staging regressed in r1). --
__global__ __launch_bounds__(256) void k_gat2_final(
    const unsigned* __restrict__ xh,                 // [N,64] uint = [N,128] bf16
    const float* __restrict__ als, const float* __restrict__ ald, // [N]
    const int* __restrict__ cnt, const int* __restrict__ ell,
    const float* __restrict__ bias2, const float* __restrict__ g2, const float* __restrict__ b2,
    const float* __restrict__ Wo, const float* __restrict__ bo,
    float* __restrict__ out)                         // [N,32]
{
  int wave = threadIdx.x>>6, t = threadIdx.x&63;
  int d = blockIdx.x*4 + wave;
  __shared__ float alphaS[4][64];
  __shared__ int   srcS[4][64];
  __shared__ float yS[4][128];
  int deg = min(cnt[d], 64);
  int s0 = ell[d*64 + t];                            // unconditional; masked below
  float add = ald[d];
  s0 = (t < deg) ? s0 : 0;
  float lg = als[s0] + add;
  float ex = (t < deg) ? __expf(lrelu02(lg)) : 0.f;
  alphaS[wave][t] = ex;
  srcS[wave][t] = s0;
  float den = ex, acc0 = 0.f, acc1 = 0.f;

  int degR = (deg + 7) & ~7;
  for (int j=0; j<degR; j+=8){                       // packed LDS + 8 loads in flight
    int4 sA4 = *(const int4*)&srcS[wave][j];
    int4 sB4 = *(const int4*)&srcS[wave][j+4];
    unsigned u[8];
    u[0] = xh[(unsigned)sA4.x*64u + t];
    u[1] = xh[(unsigned)sA4.y*64u + t];
    u[2] = xh[(unsigned)sA4.z*64u + t];
    u[3] = xh[(unsigned)sA4.w*64u + t];
    u[4] = xh[(unsigned)sB4.x*64u + t];
    u[5] = xh[(unsigned)sB4.y*64u + t];
    u[6] = xh[(unsigned)sB4.z*64u + t];
    u[7] = xh[(unsigned)sB4.w*64u + t];
    float4 aA = *(const float4*)&alphaS[wave][j];
    float4 aB = *(const float4*)&alphaS[wave][j+4];
    acc0 += aA.x*bflo(u[0]); acc1 += aA.x*bfhi(u[0]);
    acc0 += aA.y*bflo(u[1]); acc1 += aA.y*bfhi(u[1]);
    acc0 += aA.z*bflo(u[2]); acc1 += aA.z*bfhi(u[2]);
    acc0 += aA.w*bflo(u[3]); acc1 += aA.w*bfhi(u[3]);
    acc0 += aB.x*bflo(u[4]); acc1 += aB.x*bfhi(u[4]);
    acc0 += aB.y*bflo(u[5]); acc1 += aB.y*bfhi(u[5]);
    acc0 += aB.z*bflo(u[6]); acc1 += aB.z*bfhi(u[6]);
    acc0 += aB.w*bflo(u[7]); acc1 += aB.w*bfhi(u[7]);
  }
  #pragma unroll
  for (int o=32;o>0;o>>=1) den += __shfl_down(den,o);
  den = __shfl(den,0);
  float inv = 1.f/den;
  float2 bb = ((const float2*)bias2)[t];
  float v0 = acc0*inv + bb.x;
  float v1 = acc1*inv + bb.y;

  // LN(128) — single merged (sum, sumsq) tree
  float s1 = v0+v1, q = v0*v0+v1*v1;
  #pragma unroll
  for (int o=32;o>0;o>>=1){ s1 += __shfl_down(s1,o); q += __shfl_down(q,o); }
  s1 = __shfl(s1,0); q = __shfl(q,0);
  float mu = s1*(1.f/128.f);
  float var = q*(1.f/128.f) - mu*mu;
  float rs = rsqrtf(var+LN_EPS);
  float d0=v0-mu, d1=v1-mu;
  float2 gg = ((const float2*)g2)[t];
  float2 b4 = ((const float2*)b2)[t];
  float y0 = gelu_ex(d0*rs*gg.x+b4.x);
  float y1 = gelu_ex(d1*rs*gg.y+b4.y);

  // projection (128->32): stage y in wave-private LDS, broadcast-read back.
  // Same wave-local write->read idiom as alphaS/srcS above (no barrier needed).
  ((float2*)&yS[wave][0])[t] = make_float2(y0,y1);   // lane t owns ch 2t,2t+1
  int half = t>>5, c = t&31;
  const float4* y4 = (const float4*)&yS[wave][half*64];
  float part = 0.f;
  #pragma unroll
  for (int k=0;k<16;k++){
    float4 yv = y4[k];                               // broadcast per half-wave
    int ch = half*64 + k*4;
    part += yv.x*Wo[(ch+0)*32 + c] + yv.y*Wo[(ch+1)*32 + c]
          + yv.z*Wo[(ch+2)*32 + c] + yv.w*Wo[(ch+3)*32 + c];
  }
  part += __shfl_down(part, 32);                     // lanes 0..31 hold full dot
  float logit = part + bo[c];

  // log_softmax over 32 (lanes 0..31)
  float mx = logit;
  #pragma unroll
  for (int o=16;o>0;o>>=1) mx = fmaxf(mx, __shfl_xor(mx,o));
  float se = __expf(logit-mx);
  #pragma unroll
  for (int o=16;o>0;o>>=1) se += __shfl_xor(se,o);
  float lse = mx + __logf(se);
  if (t < 32) out[(size_t)d*32+t] = logit - lse;
}

extern "C" void kernel_launch(void* const* d_in, const int* in_sizes, int n_in,
                              void* d_out, int out_size, void* d_ws, size_t ws_size,
                              hipStream_t stream) {
  const float* x      = (const float*)d_in[0];
  const int*   ei     = (const int*)d_in[1];
  const float* g_in   = (const float*)d_in[2];
  const float* b_in   = (const float*)d_in[3];
  const float* W1     = (const float*)d_in[4];
  const float* att1_s = (const float*)d_in[5];
  const float* att1_d = (const float*)d_in[6];
  const float* bias1  = (const float*)d_in[7];
  const float* g1     = (const float*)d_in[8];
  const float* b1     = (const float*)d_in[9];
  const float* W2     = (const float*)d_in[10];
  const float* att2_s = (const float*)d_in[11];
  const float* att2_d = (const float*)d_in[12];
  const float* bias2  = (const float*)d_in[13];
  const float* g2     = (const float*)d_in[14];
  const float* b2     = (const float*)d_in[15];
  const float* Wo     = (const float*)d_in[16];
  const float* bo     = (const float*)d_in[17];
  float* out = (float*)d_out;

  char* ws = (char*)d_ws;
  size_t off = 0;
  auto alloc = [&](size_t bytes)->char*{
    char* p = ws + off; off += (bytes + 255) & ~(size_t)255; return p;
  };
  unsigned* h0b   = (unsigned*)alloc((size_t)N_NODES*128*2);       // LN(x) bf16 table
  unsigned short* xh2b = (unsigned short*)alloc((size_t)N_NODES*128*2); // fused GEMM2 out bf16
  float*    als1  = (float*)alloc((size_t)N_NODES*4*4);
  float*    ald1  = (float*)alloc((size_t)N_NODES*4*4);
  float*    als2  = (float*)alloc((size_t)N_NODES*4);
  float*    ald2  = (float*)alloc((size_t)N_NODES*4);
  int*      cnt   = (int*)alloc((size_t)N_NODES*4);
  int*      ell   = (int*)alloc((size_t)N_NODES*64*4);             // ELL adjacency
  unsigned short* W1t = (unsigned short*)alloc((size_t)512*128*2); // [512][128] bf16
  unsigned short* W2t = (unsigned short*)alloc((size_t)128*512*2); // [128][512] bf16
  float*    wtil  = (float*)alloc((size_t)8*128*4);                // fused logit vecs

  // 1. weight transposes + parallel w~ + zero cnt
  k_prep<<<TB1 + TB2 + WTB + ZCB,256,0,stream>>>(W1, W2, att1_s, att1_d,
                                                 W1t, W2t, wtil, cnt);
  // 2. ELL build + input LN + fp32 att1 logits
  k_build_mega<<<EBL + LNB,256,0,stream>>>(ei, cnt, ell, x, g_in, b_in, wtil,
                                           h0b, (float4*)als1, (float4*)ald1);
  // 3. GAT1 in input space + W1-proj MFMA + LN/GELU + fused GEMM2 + att2 logits
  k_gat1_fused<<<N_NODES/16,512,0,stream>>>(h0b,
      (const float4*)als1, (const float4*)ald1, cnt, ell,
      bias1, g1, b1, W1t, W2t, att2_s, att2_d, xh2b, als2, ald2);
  // 4. GAT layer 2 + Wo projection + log_softmax
  k_gat2_final<<<N_NODES/4,256,0,stream>>>((const unsigned*)xh2b, als2, ald2,
      cnt, ell, bias2, g2, b2, Wo, bo, out);
}

// Round 4
// 214.218 us; speedup vs baseline: 1.0466x; 1.0082x over previous
//
#include <hip/hip_runtime.h>
#include <hip/hip_bf16.h>
#include <math.h>

static constexpr int N_NODES = 20000;
static constexpr int N_EDGES = 320000;
static constexpr int ETOT    = N_EDGES + N_NODES;   // edges + self loops
static constexpr float LN_EPS = 1e-5f;

__device__ __forceinline__ float lrelu02(float x){ return x > 0.f ? x : 0.2f*x; }
__device__ __forceinline__ float gelu_ex(float x){ return 0.5f*x*(1.f+erff(x*0.70710678118654752f)); }
__device__ __forceinline__ float bflo(unsigned u){ return __uint_as_float(u<<16); }
__device__ __forceinline__ float bfhi(unsigned u){ return __uint_as_float(u & 0xffff0000u); }
__device__ __forceinline__ unsigned f2bf(float f){           // RNE fp32->bf16
  unsigned u = __float_as_uint(f);
  return (u + 0x7fffu + ((u>>16)&1u)) >> 16;
}
__device__ __forceinline__ unsigned packbf2(float a, float b){ return f2bf(a) | (f2bf(b)<<16); }

typedef __attribute__((ext_vector_type(8))) short bf16x8;
typedef __attribute__((ext_vector_type(4))) float f32x4;
typedef __attribute__((ext_vector_type(2))) float f32x2;
union BF8 { unsigned short us[8]; bf16x8 v; uint4 u4; };

// ---- packed f32 FMA (VOP3P). d.lo = a.lo*b.lo + c.lo etc.
// pkfma    : d = a*b + c (both halves independent)
// pkfma_lo : b.LO broadcast to both halves  (op_sel_hi:[1,0,1])
// pkfma_hi : b.HI broadcast to both halves  (op_sel:[0,1,0] op_sel_hi:[1,1,1])
__device__ __forceinline__ void pkfma(f32x2& c, f32x2 a, f32x2 b){
  asm("v_pk_fma_f32 %0, %1, %2, %0" : "+v"(c) : "v"(a), "v"(b));
}
__device__ __forceinline__ void pkfma_lo(f32x2& c, f32x2 a, f32x2 b){
  asm("v_pk_fma_f32 %0, %1, %2, %0 op_sel_hi:[1,0,1]" : "+v"(c) : "v"(a), "v"(b));
}
__device__ __forceinline__ void pkfma_hi(f32x2& c, f32x2 a, f32x2 b){
  asm("v_pk_fma_f32 %0, %1, %2, %0 op_sel:[0,1,0] op_sel_hi:[1,1,1]" : "+v"(c) : "v"(a), "v"(b));
}

// ---- prep: weight transposes + PARALLEL w~ + zero cnt ----
static constexpr int TB1 = 512*128/256;             // 256 blocks W1t
static constexpr int TB2 = 512*128/256;             // 256 blocks W2t
static constexpr int WTB = 128;                     // 128 blocks wtil (8 outs ea, 32 thr/out)
static constexpr int ZCB = (N_NODES + 255)/256;     // 79 blocks zero-cnt
__global__ __launch_bounds__(256) void k_prep(
    const float* __restrict__ W1, const float* __restrict__ W2,
    const float* __restrict__ att1_s, const float* __restrict__ att1_d,
    unsigned short* __restrict__ W1t, unsigned short* __restrict__ W2t,
    float* __restrict__ wtil, int* __restrict__ cnt) {
  int b = blockIdx.x, tid = threadIdx.x;
  if (b < TB1){                                     // W1t[n][k]=bf16(W1[k][n]) K=128,N=512
    int idx = b*256 + tid;
    int n = idx >> 7, k = idx & 127;
    W1t[idx] = (unsigned short)f2bf(W1[(size_t)k*512 + n]);
    return;
  }
  if (b < TB1 + TB2){                               // W2t[n][k]=bf16(W2[k][n]) K=512,N=128
    int idx = (b-TB1)*256 + tid;
    int n = idx >> 9, k = idx & 511;
    W2t[idx] = (unsigned short)f2bf(W2[(size_t)k*128 + n]);
    return;
  }
  if (b < TB1 + TB2 + WTB){
    // wtil[v*128+k] = sum_c W1[k, (v&3)*128+c]*att{s|d}[(v&3),c]; 32 thr/output
    int o = (b-TB1-TB2)*8 + (tid>>5);               // 0..1023
    int c32 = tid & 31;
    int v = o >> 7, k = o & 127, h = v & 3;
    const float* av = (v < 4) ? (att1_s + h*128) : (att1_d + h*128);
    const float* wr = W1 + (size_t)k*512 + h*128;
    float p = wr[c32]*av[c32] + wr[c32+32]*av[c32+32]
            + wr[c32+64]*av[c32+64] + wr[c32+96]*av[c32+96];
    #pragma unroll
    for (int o2=1;o2<32;o2<<=1) p += __shfl_xor(p, o2);
    if (c32 == 0) wtil[o] = p;
    return;
  }
  int idx = (b - TB1 - TB2 - WTB)*256 + tid;        // zero cnt
  if (idx < N_NODES) cnt[idx] = 0;
}

// ---- mega kernel: ELL build (atomic slots) + input LN + fp32 att1 logits ----
static constexpr int EBL = (ETOT + 255)/256;        // 1329 edge blocks
static constexpr int LNB = N_NODES/4;               // 5000 LN blocks (4 rows ea)
__global__ __launch_bounds__(256) void k_build_mega(
    const int* __restrict__ ei, int* __restrict__ cnt, int* __restrict__ ell,
    const float* __restrict__ x, const float* __restrict__ g_in,
    const float* __restrict__ b_in, const float* __restrict__ wtil,
    unsigned* __restrict__ h0b, float4* __restrict__ als4, float4* __restrict__ ald4) {
  int b = blockIdx.x, tid = threadIdx.x;
  if (b < EBL){                                     // ELL scatter (deg<=64 w.h.p.)
    int e = b*256 + tid;
    int s, d;
    if (e < N_EDGES){ s = ei[e]; d = ei[N_EDGES+e]; }
    else if (e < ETOT){ s = e - N_EDGES; d = s; }
    else return;
    int pos = atomicAdd(&cnt[d], 1);
    if (pos < 64) ell[d*64 + pos] = s;
    return;
  }
  // LN over 128-ch rows -> bf16 h0b; logits als/ald = h0 . w~ (fp32 exact)
  int row = (b - EBL)*4 + (tid>>6);
  int t = tid & 63;
  float2 v = ((const float2*)(x + (size_t)row*128))[t];
  float s = v.x + v.y;
  float q = v.x*v.x + v.y*v.y;
  #pragma unroll
  for (int o=32;o>0;o>>=1){ s += __shfl_down(s,o); q += __shfl_down(q,o); }
  s = __shfl(s,0); q = __shfl(q,0);
  float mu = s*(1.f/128.f);
  float var = q*(1.f/128.f) - mu*mu;
  float rs = rsqrtf(var+LN_EPS);
  float d0 = v.x-mu, d1 = v.y-mu;
  float2 gg = ((const float2*)g_in)[t];
  float2 bb = ((const float2*)b_in)[t];
  float y0 = d0*rs*gg.x+bb.x;
  float y1 = d1*rs*gg.y+bb.y;
  h0b[(size_t)row*64 + t] = packbf2(y0,y1);
  float ps[4], pd[4];
  #pragma unroll
  for (int h=0;h<4;h++){
    float2 ws = ((const float2*)(wtil + h*128))[t];
    float2 wd = ((const float2*)(wtil + (4+h)*128))[t];
    ps[h] = y0*ws.x + y1*ws.y;
    pd[h] = y0*wd.x + y1*wd.y;
  }
  #pragma unroll
  for (int o=1;o<64;o<<=1){
    #pragma unroll
    for (int h=0;h<4;h++){ ps[h]+=__shfl_xor(ps[h],o); pd[h]+=__shfl_xor(pd[h],o); }
  }
  if (t==0){
    als4[row] = make_float4(ps[0],ps[1],ps[2],ps[3]);
    ald4[row] = make_float4(pd[0],pd[1],pd[2],pd[3]);
  }
}

// ---- GAT1 in input space + W1-proj MFMA + LN/GELU + GEMM2 + att2 ----
// r18: gather inner loop uses v_pk_fma_f32 (16 FMA -> 4 pk_fma per edge;
// op_sel broadcasts v.lo/v.hi, alpha pairs free from the float4 LDS read).
// acc pairs: P0={h0lo,h1lo} P1={h2lo,h3lo} P2={h0hi,h1hi} P3={h2hi,h3hi}.
__global__ __launch_bounds__(512) void k_gat1_fused(
    const unsigned* __restrict__ h0,                 // [N][64] uint = [N,128] bf16
    const float4* __restrict__ als4, const float4* __restrict__ ald4, // [N]
    const int* __restrict__ cnt, const int* __restrict__ ell,
    const float* __restrict__ bias1, const float* __restrict__ g1, const float* __restrict__ b1,
    const unsigned short* __restrict__ W1t,          // [512][128] bf16
    const unsigned short* __restrict__ W2t,          // [128][512] bf16
    const float* __restrict__ att2_s, const float* __restrict__ att2_d, // [128]
    unsigned short* __restrict__ xh2b,               // [N,128] bf16
    float* __restrict__ als2, float* __restrict__ ald2) // [N]
{
  __shared__ unsigned short AggHi[16*520];           // reused as h1 tile later
  __shared__ float4 alphaW4[8][64];                  // 4 head-alphas packed per slot
  __shared__ int   srcW[8][64];
  __shared__ float scrA[8][16], scrB[8][16];
  __shared__ float scrS[8][16], scrD[8][16];
  int dstbase = blockIdx.x*16;
  int tid = threadIdx.x, wave = tid>>6, lane = tid&63;
  int kq = lane>>4, l15 = lane&15;

  // ---- Phase A: descriptors upfront (cheap), als4 staged 1-deep ----
  int degP[2], sP[2];
  float4 adP[2];
  #pragma unroll
  for (int r=0;r<2;r++){
    int d = dstbase + r*8 + wave;
    degP[r] = min(cnt[d],64);
    sP[r]   = ell[d*64 + lane];                      // unconditional
    adP[r]  = ald4[d];
  }
  #pragma unroll
  for (int r=0;r<2;r++) sP[r] = (lane < degP[r]) ? sP[r] : 0;
  float4 asCur = als4[sP[0]];

  unsigned* Hi = (unsigned*)AggHi;
  #pragma unroll
  for (int r=0; r<2; r++){
    float4 asNext;
    if (r < 1) asNext = als4[sP[1]];                 // in flight during this round
    int row = r*8 + wave;                            // 0..15
    int deg = degP[r];
    float4 ad_ = adP[r];
    float e0=0.f,e1=0.f,e2=0.f,e3=0.f;
    if (lane < deg){
      e0 = __expf(lrelu02(asCur.x+ad_.x));
      e1 = __expf(lrelu02(asCur.y+ad_.y));
      e2 = __expf(lrelu02(asCur.z+ad_.z));
      e3 = __expf(lrelu02(asCur.w+ad_.w));
    }
    srcW[wave][lane] = sP[r];
    alphaW4[wave][lane] = make_float4(e0,e1,e2,e3);
    float q0=e0,q1=e1,q2=e2,q3=e3;
    #pragma unroll
    for (int o=1;o<64;o<<=1){
      q0+=__shfl_xor(q0,o); q1+=__shfl_xor(q1,o);
      q2+=__shfl_xor(q2,o); q3+=__shfl_xor(q3,o);
    }
    float inv[4] = {1.f/q0, 1.f/q1, 1.f/q2, 1.f/q3};

    f32x2 accP0={0.f,0.f}, accP1={0.f,0.f}, accP2={0.f,0.f}, accP3={0.f,0.f};
    int degR = (deg + 7) & ~7;
    for (int j=0; j<degR; j+=8){                     // 8 loads in flight
      int4 sA4 = *(const int4*)&srcW[wave][j];       // packed src reads
      int4 sB4 = *(const int4*)&srcW[wave][j+4];
      unsigned v[8];
      v[0] = h0[(unsigned)sA4.x*64u + lane];
      v[1] = h0[(unsigned)sA4.y*64u + lane];
      v[2] = h0[(unsigned)sA4.z*64u + lane];
      v[3] = h0[(unsigned)sA4.w*64u + lane];
      v[4] = h0[(unsigned)sB4.x*64u + lane];
      v[5] = h0[(unsigned)sB4.y*64u + lane];
      v[6] = h0[(unsigned)sB4.z*64u + lane];
      v[7] = h0[(unsigned)sB4.w*64u + lane];
      #pragma unroll
      for (int i=0;i<8;i++){
        float4 a = alphaW4[wave][j+i];               // ONE b128 broadcast/edge
        f32x2 a01 = {a.x, a.y}, a23 = {a.z, a.w};
        f32x2 vv  = {bflo(v[i]), bfhi(v[i])};
        pkfma_lo(accP0, a01, vv);                    // {h0,h1} x lo
        pkfma_lo(accP1, a23, vv);                    // {h2,h3} x lo
        pkfma_hi(accP2, a01, vv);                    // {h0,h1} x hi
        pkfma_hi(accP3, a23, vv);                    // {h2,h3} x hi
      }
    }
    // normalize; lane owns ch pair (2*lane, 2*lane+1) per head; bf16 pack
    Hi[row*260 + 0*64 + lane] = packbf2(accP0.x*inv[0], accP2.x*inv[0]);
    Hi[row*260 + 1*64 + lane] = packbf2(accP0.y*inv[1], accP2.y*inv[1]);
    Hi[row*260 + 2*64 + lane] = packbf2(accP1.x*inv[2], accP3.x*inv[2]);
    Hi[row*260 + 3*64 + lane] = packbf2(accP1.y*inv[3], accP3.y*inv[3]);
    if (r < 1) asCur = asNext;
  }
  __syncthreads();

  // ---- Phase B: W1 projection; wave covers cols [wave*64, wave*64+64), head = wave>>1 ----
  f32x4 acc1[4] = {};
  {
    const uint4* Hi4 = (const uint4*)AggHi;
    int h = wave>>1;
    #pragma unroll
    for (int kt=0; kt<4; kt++){
      BF8 fh;
      fh.u4 = Hi4[(size_t)l15*65 + h*16 + kt*4 + kq];
      #pragma unroll
      for (int ct=0; ct<4; ct++){
        int col = wave*64 + ct*16 + l15;
        BF8 fb; fb.u4 = *(const uint4*)&W1t[(size_t)col*128 + kt*32 + kq*8];
        acc1[ct] = __builtin_amdgcn_mfma_f32_16x16x32_bf16(fh.v, fb.v, acc1[ct], 0,0,0);
      }
    }
  }
  // epilogue: bias + LN(512) + GELU; single-pass sum+sumsq -> ONE barrier
  float vloc[4][4];
  float sum_r[4] = {0,0,0,0}, sq_r[4] = {0,0,0,0};
  #pragma unroll
  for (int ct=0; ct<4; ct++){
    int col = wave*64 + ct*16 + l15;
    float bb = bias1[col];
    #pragma unroll
    for (int r=0;r<4;r++){
      float v = acc1[ct][r] + bb;
      vloc[ct][r] = v;
      sum_r[r] += v;
      sq_r[r]  += v*v;
    }
  }
  #pragma unroll
  for (int o=1;o<16;o<<=1)
    #pragma unroll
    for (int r=0;r<4;r++){ sum_r[r] += __shfl_xor(sum_r[r], o); sq_r[r] += __shfl_xor(sq_r[r], o); }
  if (l15 == 0){
    #pragma unroll
    for (int r=0;r<4;r++){ scrA[wave][kq*4+r] = sum_r[r]; scrB[wave][kq*4+r] = sq_r[r]; }
  }
  __syncthreads();                                   // also: all MFMA A-frag reads done
  unsigned short* h1s = AggHi;                       // reuse (reads complete)
  #pragma unroll
  for (int r=0;r<4;r++){
    int m = kq*4+r;
    float s_ = 0.f, vs = 0.f;
    #pragma unroll
    for (int w=0;w<8;w++){ s_ += scrA[w][m]; vs += scrB[w][m]; }
    float mu = s_*(1.f/512.f);
    float var = vs*(1.f/512.f) - mu*mu;
    float rsv = rsqrtf(var+LN_EPS);
    #pragma unroll
    for (int ct=0; ct<4; ct++){
      int col = wave*64 + ct*16 + l15;
      float y = gelu_ex((vloc[ct][r]-mu)*rsv*g1[col] + b1[col]);
      h1s[(size_t)m*520 + col] = (unsigned short)f2bf(y);
    }
  }
  __syncthreads();

  // ---- Phase C: fused GEMM2 (wave covers out-cols [wave*16, +16)); K=512 ----
  f32x4 acc2 = {};
  const uint4* h1s4 = (const uint4*)h1s;
  int colc = wave*16 + l15;
  #pragma unroll
  for (int kt=0; kt<16; kt++){
    BF8 fa; fa.u4 = h1s4[(size_t)l15*65 + kt*4 + kq];
    BF8 fb; fb.u4 = *(const uint4*)&W2t[(size_t)colc*512 + kt*32 + kq*8];
    acc2 = __builtin_amdgcn_mfma_f32_16x16x32_bf16(fa.v, fb.v, acc2, 0,0,0);
  }
  float ps[4], pd[4];
  {
    float ws = att2_s[colc], wd = att2_d[colc];
    #pragma unroll
    for (int r2=0; r2<4; r2++){
      float vv = acc2[r2];
      xh2b[(size_t)(dstbase + kq*4 + r2)*128 + colc] = (unsigned short)f2bf(vv);
      ps[r2] = vv*ws; pd[r2] = vv*wd;
    }
  }
  #pragma unroll
  for (int o=1;o<16;o<<=1){
    #pragma unroll
    for (int r2=0;r2<4;r2++){ ps[r2]+=__shfl_xor(ps[r2],o); pd[r2]+=__shfl_xor(pd[r2],o); }
  }
  if (l15 == 0){
    #pragma unroll
    for (int r2=0;r2<4;r2++){
      scrS[wave][kq*4+r2] = ps[r2];
      scrD[wave][kq*4+r2] = pd[r2];
    }
  }
  __syncthreads();
  if (tid < 16){
    float ss = 0.f, sd = 0.f;
    #pragma unroll
    for (int w=0;w<8;w++){ ss += scrS[w][tid]; sd += scrD[w][tid]; }
    als2[dstbase+tid] = ss;
    ald2[dstbase+tid] = sd;
  }
}

// -- GAT layer 2: bf16 table, 4 nodes/block (wave=node); packed LDS reads;
//    r18: pk_fma in gather (1 instr per edge: alpha pair serves 2 edges via
//    lo/hi op_sel) and in Wo projection (64 FMA -> 32 pk_fma).
//    Wo direct loads (16KB = L1-resident; staging regressed in r1). --
__global__ __launch_bounds__(256) void k_gat2_final(
    const unsigned* __restrict__ xh,                 // [N,64] uint = [N,128] bf16
    const float* __restrict__ als, const float* __restrict__ ald, // [N]
    const int* __restrict__ cnt, const int* __restrict__ ell,
    const float* __restrict__ bias2, const float* __restrict__ g2, const float* __restrict__ b2,
    const float* __restrict__ Wo, const float* __restrict__ bo,
    float* __restrict__ out)                         // [N,32]
{
  int wave = threadIdx.x>>6, t = threadIdx.x&63;
  int d = blockIdx.x*4 + wave;
  __shared__ float alphaS[4][64];
  __shared__ int   srcS[4][64];
  __shared__ float yS[4][128];
  int deg = min(cnt[d], 64);
  int s0 = ell[d*64 + t];                            // unconditional; masked below
  float add = ald[d];
  s0 = (t < deg) ? s0 : 0;
  float lg = als[s0] + add;
  float ex = (t < deg) ? __expf(lrelu02(lg)) : 0.f;
  alphaS[wave][t] = ex;
  srcS[wave][t] = s0;
  float den = ex;
  f32x2 accP = {0.f, 0.f};                           // {lo-ch, hi-ch}

  int degR = (deg + 7) & ~7;
  for (int j=0; j<degR; j+=8){                       // packed LDS + 8 loads in flight
    int4 sA4 = *(const int4*)&srcS[wave][j];
    int4 sB4 = *(const int4*)&srcS[wave][j+4];
    unsigned u[8];
    u[0] = xh[(unsigned)sA4.x*64u + t];
    u[1] = xh[(unsigned)sA4.y*64u + t];
    u[2] = xh[(unsigned)sA4.z*64u + t];
    u[3] = xh[(unsigned)sA4.w*64u + t];
    u[4] = xh[(unsigned)sB4.x*64u + t];
    u[5] = xh[(unsigned)sB4.y*64u + t];
    u[6] = xh[(unsigned)sB4.z*64u + t];
    u[7] = xh[(unsigned)sB4.w*64u + t];
    float4 aA = *(const float4*)&alphaS[wave][j];
    float4 aB = *(const float4*)&alphaS[wave][j+4];
    f32x2 aXY = {aA.x, aA.y}, aZW = {aA.z, aA.w};
    f32x2 bXY = {aB.x, aB.y}, bZW = {aB.z, aB.w};
    f32x2 v0 = {bflo(u[0]), bfhi(u[0])};
    f32x2 v1 = {bflo(u[1]), bfhi(u[1])};
    f32x2 v2 = {bflo(u[2]), bfhi(u[2])};
    f32x2 v3 = {bflo(u[3]), bfhi(u[3])};
    f32x2 v4 = {bflo(u[4]), bfhi(u[4])};
    f32x2 v5 = {bflo(u[5]), bfhi(u[5])};
    f32x2 v6 = {bflo(u[6]), bfhi(u[6])};
    f32x2 v7 = {bflo(u[7]), bfhi(u[7])};
    pkfma_lo(accP, v0, aXY);                         // += v0 * aA.x
    pkfma_hi(accP, v1, aXY);                         // += v1 * aA.y
    pkfma_lo(accP, v2, aZW);
    pkfma_hi(accP, v3, aZW);
    pkfma_lo(accP, v4, bXY);
    pkfma_hi(accP, v5, bXY);
    pkfma_lo(accP, v6, bZW);
    pkfma_hi(accP, v7, bZW);
  }
  #pragma unroll
  for (int o=32;o>0;o>>=1) den += __shfl_down(den,o);
  den = __shfl(den,0);
  float inv = 1.f/den;
  float2 bb = ((const float2*)bias2)[t];
  float v0 = accP.x*inv + bb.x;
  float v1 = accP.y*inv + bb.y;

  // LN(128) — single merged (sum, sumsq) tree
  float s1 = v0+v1, q = v0*v0+v1*v1;
  #pragma unroll
  for (int o=32;o>0;o>>=1){ s1 += __shfl_down(s1,o); q += __shfl_down(q,o); }
  s1 = __shfl(s1,0); q = __shfl(q,0);
  float mu = s1*(1.f/128.f);
  float var = q*(1.f/128.f) - mu*mu;
  float rs = rsqrtf(var+LN_EPS);
  float d0=v0-mu, d1=v1-mu;
  float2 gg = ((const float2*)g2)[t];
  float2 b4 = ((const float2*)b2)[t];
  float y0 = gelu_ex(d0*rs*gg.x+b4.x);
  float y1 = gelu_ex(d1*rs*gg.y+b4.y);

  // projection (128->32): stage y in wave-private LDS, broadcast-read back.
  ((float2*)&yS[wave][0])[t] = make_float2(y0,y1);   // lane t owns ch 2t,2t+1
  int half = t>>5, c = t&31;
  const float4* y4 = (const float4*)&yS[wave][half*64];
  f32x2 partP = {0.f, 0.f};                          // {even-ch, odd-ch} partials
  #pragma unroll
  for (int k=0;k<16;k++){
    float4 yv = y4[k];                               // broadcast per half-wave
    int ch = half*64 + k*4;
    f32x2 w01 = {Wo[(ch+0)*32 + c], Wo[(ch+1)*32 + c]};
    f32x2 w23 = {Wo[(ch+2)*32 + c], Wo[(ch+3)*32 + c]};
    f32x2 yxy = {yv.x, yv.y}, yzw = {yv.z, yv.w};
    pkfma(partP, yxy, w01);
    pkfma(partP, yzw, w23);
  }
  float part = partP.x + partP.y;
  part += __shfl_down(part, 32);                     // lanes 0..31 hold full dot
  float logit = part + bo[c];

  // log_softmax over 32 (lanes 0..31)
  float mx = logit;
  #pragma unroll
  for (int o=16;o>0;o>>=1) mx = fmaxf(mx, __shfl_xor(mx,o));
  float se = __expf(logit-mx);
  #pragma unroll
  for (int o=16;o>0;o>>=1) se += __shfl_xor(se,o);
  float lse = mx + __logf(se);
  if (t < 32) out[(size_t)d*32+t] = logit - lse;
}

extern "C" void kernel_launch(void* const* d_in, const int* in_sizes, int n_in,
                              void* d_out, int out_size, void* d_ws, size_t ws_size,
                              hipStream_t stream) {
  const float* x      = (const float*)d_in[0];
  const int*   ei     = (const int*)d_in[1];
  const float* g_in   = (const float*)d_in[2];
  const float* b_in   = (const float*)d_in[3];
  const float* W1     = (const float*)d_in[4];
  const float* att1_s = (const float*)d_in[5];
  const float* att1_d = (const float*)d_in[6];
  const float* bias1  = (const float*)d_in[7];
  const float* g1     = (const float*)d_in[8];
  const float* b1     = (const float*)d_in[9];
  const float* W2     = (const float*)d_in[10];
  const float* att2_s = (const float*)d_in[11];
  const float* att2_d = (const float*)d_in[12];
  const float* bias2  = (const float*)d_in[13];
  const float* g2     = (const float*)d_in[14];
  const float* b2     = (const float*)d_in[15];
  const float* Wo     = (const float*)d_in[16];
  const float* bo     = (const float*)d_in[17];
  float* out = (float*)d_out;

  char* ws = (char*)d_ws;
  size_t off = 0;
  auto alloc = [&](size_t bytes)->char*{
    char* p = ws + off; off += (bytes + 255) & ~(size_t)255; return p;
  };
  unsigned* h0b   = (unsigned*)alloc((size_t)N_NODES*128*2);       // LN(x) bf16 table
  unsigned short* xh2b = (unsigned short*)alloc((size_t)N_NODES*128*2); // fused GEMM2 out bf16
  float*    als1  = (float*)alloc((size_t)N_NODES*4*4);
  float*    ald1  = (float*)alloc((size_t)N_NODES*4*4);
  float*    als2  = (float*)alloc((size_t)N_NODES*4);
  float*    ald2  = (float*)alloc((size_t)N_NODES*4);
  int*      cnt   = (int*)alloc((size_t)N_NODES*4);
  int*      ell   = (int*)alloc((size_t)N_NODES*64*4);             // ELL adjacency
  unsigned short* W1t = (unsigned short*)alloc((size_t)512*128*2); // [512][128] bf16
  unsigned short* W2t = (unsigned short*)alloc((size_t)128*512*2); // [128][512] bf16
  float*    wtil  = (float*)alloc((size_t)8*128*4);                // fused logit vecs

  // 1. weight transposes + parallel w~ + zero cnt
  k_prep<<<TB1 + TB2 + WTB + ZCB,256,0,stream>>>(W1, W2, att1_s, att1_d,
                                                 W1t, W2t, wtil, cnt);
  // 2. ELL build + input LN + fp32 att1 logits
  k_build_mega<<<EBL + LNB,256,0,stream>>>(ei, cnt, ell, x, g_in, b_in, wtil,
                                           h0b, (float4*)als1, (float4*)ald1);
  // 3. GAT1 in input space + W1-proj MFMA + LN/GELU + fused GEMM2 + att2 logits
  k_gat1_fused<<<N_NODES/16,512,0,stream>>>(h0b,
      (const float4*)als1, (const float4*)ald1, cnt, ell,
      bias1, g1, b1, W1t, W2t, att2_s, att2_d, xh2b, als2, ald2);
  // 4. GAT layer 2 + Wo projection + log_softmax
  k_gat2_final<<<N_NODES/4,256,0,stream>>>((const unsigned*)xh2b, als2, ald2,
      cnt, ell, bias2, g2, b2, Wo, bo, out);
}

// Round 5
// 211.707 us; speedup vs baseline: 1.0590x; 1.0119x over previous
//
#include <hip/hip_runtime.h>
#include <hip/hip_bf16.h>
#include <math.h>

static constexpr int N_NODES = 20000;
static constexpr int N_EDGES = 320000;
static constexpr int ETOT    = N_EDGES + N_NODES;   // edges + self loops
static constexpr float LN_EPS = 1e-5f;

__device__ __forceinline__ float lrelu02(float x){ return x > 0.f ? x : 0.2f*x; }
__device__ __forceinline__ float gelu_ex(float x){ return 0.5f*x*(1.f+erff(x*0.70710678118654752f)); }
__device__ __forceinline__ float bflo(unsigned u){ return __uint_as_float(u<<16); }
__device__ __forceinline__ float bfhi(unsigned u){ return __uint_as_float(u & 0xffff0000u); }
__device__ __forceinline__ unsigned f2bf(float f){           // RNE fp32->bf16
  unsigned u = __float_as_uint(f);
  return (u + 0x7fffu + ((u>>16)&1u)) >> 16;
}
__device__ __forceinline__ unsigned packbf2(float a, float b){ return f2bf(a) | (f2bf(b)<<16); }

typedef __attribute__((ext_vector_type(8))) short bf16x8;
typedef __attribute__((ext_vector_type(4))) float f32x4;
typedef __attribute__((ext_vector_type(2))) float f32x2;
union BF8 { unsigned short us[8]; bf16x8 v; uint4 u4; };

// ---- packed f32 FMA (VOP3P). d.lo = a.lo*b.lo + c.lo etc.
__device__ __forceinline__ void pkfma(f32x2& c, f32x2 a, f32x2 b){
  asm("v_pk_fma_f32 %0, %1, %2, %0" : "+v"(c) : "v"(a), "v"(b));
}
__device__ __forceinline__ void pkfma_lo(f32x2& c, f32x2 a, f32x2 b){
  asm("v_pk_fma_f32 %0, %1, %2, %0 op_sel_hi:[1,0,1]" : "+v"(c) : "v"(a), "v"(b));
}
__device__ __forceinline__ void pkfma_hi(f32x2& c, f32x2 a, f32x2 b){
  asm("v_pk_fma_f32 %0, %1, %2, %0 op_sel:[0,1,0] op_sel_hi:[1,1,1]" : "+v"(c) : "v"(a), "v"(b));
}

// ---- prep: weight transposes + PARALLEL w~ + zero cnt ----
static constexpr int TB1 = 512*128/256;             // 256 blocks W1t
static constexpr int TB2 = 512*128/256;             // 256 blocks W2t
static constexpr int WTB = 128;                     // 128 blocks wtil (8 outs ea, 32 thr/out)
static constexpr int ZCB = (N_NODES + 255)/256;     // 79 blocks zero-cnt
__global__ __launch_bounds__(256) void k_prep(
    const float* __restrict__ W1, const float* __restrict__ W2,
    const float* __restrict__ att1_s, const float* __restrict__ att1_d,
    unsigned short* __restrict__ W1t, unsigned short* __restrict__ W2t,
    float* __restrict__ wtil, int* __restrict__ cnt) {
  int b = blockIdx.x, tid = threadIdx.x;
  if (b < TB1){                                     // W1t[n][k]=bf16(W1[k][n]) K=128,N=512
    int idx = b*256 + tid;
    int n = idx >> 7, k = idx & 127;
    W1t[idx] = (unsigned short)f2bf(W1[(size_t)k*512 + n]);
    return;
  }
  if (b < TB1 + TB2){                               // W2t[n][k]=bf16(W2[k][n]) K=512,N=128
    int idx = (b-TB1)*256 + tid;
    int n = idx >> 9, k = idx & 511;
    W2t[idx] = (unsigned short)f2bf(W2[(size_t)k*128 + n]);
    return;
  }
  if (b < TB1 + TB2 + WTB){
    // wtil[v*128+k] = sum_c W1[k, (v&3)*128+c]*att{s|d}[(v&3),c]; 32 thr/output
    int o = (b-TB1-TB2)*8 + (tid>>5);               // 0..1023
    int c32 = tid & 31;
    int v = o >> 7, k = o & 127, h = v & 3;
    const float* av = (v < 4) ? (att1_s + h*128) : (att1_d + h*128);
    const float* wr = W1 + (size_t)k*512 + h*128;
    float p = wr[c32]*av[c32] + wr[c32+32]*av[c32+32]
            + wr[c32+64]*av[c32+64] + wr[c32+96]*av[c32+96];
    #pragma unroll
    for (int o2=1;o2<32;o2<<=1) p += __shfl_xor(p, o2);
    if (c32 == 0) wtil[o] = p;
    return;
  }
  int idx = (b - TB1 - TB2 - WTB)*256 + tid;        // zero cnt
  if (idx < N_NODES) cnt[idx] = 0;
}

// ---- mega kernel: ELL build (atomic slots) + input LN + fp32 att1 logits ----
static constexpr int EBL = (ETOT + 255)/256;        // 1329 edge blocks
static constexpr int LNB = N_NODES/4;               // 5000 LN blocks (4 rows ea)
__global__ __launch_bounds__(256) void k_build_mega(
    const int* __restrict__ ei, int* __restrict__ cnt, int* __restrict__ ell,
    const float* __restrict__ x, const float* __restrict__ g_in,
    const float* __restrict__ b_in, const float* __restrict__ wtil,
    unsigned* __restrict__ h0b, float4* __restrict__ als4, float4* __restrict__ ald4) {
  int b = blockIdx.x, tid = threadIdx.x;
  if (b < EBL){                                     // ELL scatter (deg<=64 w.h.p.)
    int e = b*256 + tid;
    int s, d;
    if (e < N_EDGES){ s = ei[e]; d = ei[N_EDGES+e]; }
    else if (e < ETOT){ s = e - N_EDGES; d = s; }
    else return;
    int pos = atomicAdd(&cnt[d], 1);
    if (pos < 64) ell[d*64 + pos] = s;
    return;
  }
  // LN over 128-ch rows -> bf16 h0b; logits als/ald = h0 . w~ (fp32 exact)
  int row = (b - EBL)*4 + (tid>>6);
  int t = tid & 63;
  float2 v = ((const float2*)(x + (size_t)row*128))[t];
  float s = v.x + v.y;
  float q = v.x*v.x + v.y*v.y;
  #pragma unroll
  for (int o=32;o>0;o>>=1){ s += __shfl_down(s,o); q += __shfl_down(q,o); }
  s = __shfl(s,0); q = __shfl(q,0);
  float mu = s*(1.f/128.f);
  float var = q*(1.f/128.f) - mu*mu;
  float rs = rsqrtf(var+LN_EPS);
  float d0 = v.x-mu, d1 = v.y-mu;
  float2 gg = ((const float2*)g_in)[t];
  float2 bb = ((const float2*)b_in)[t];
  float y0 = d0*rs*gg.x+bb.x;
  float y1 = d1*rs*gg.y+bb.y;
  h0b[(size_t)row*64 + t] = packbf2(y0,y1);
  float ps[4], pd[4];
  #pragma unroll
  for (int h=0;h<4;h++){
    float2 ws = ((const float2*)(wtil + h*128))[t];
    float2 wd = ((const float2*)(wtil + (4+h)*128))[t];
    ps[h] = y0*ws.x + y1*ws.y;
    pd[h] = y0*wd.x + y1*wd.y;
  }
  #pragma unroll
  for (int o=1;o<64;o<<=1){
    #pragma unroll
    for (int h=0;h<4;h++){ ps[h]+=__shfl_xor(ps[h],o); pd[h]+=__shfl_xor(pd[h],o); }
  }
  if (t==0){
    als4[row] = make_float4(ps[0],ps[1],ps[2],ps[3]);
    ald4[row] = make_float4(pd[0],pd[1],pd[2],pd[3]);
  }
}

// ---- GAT1 in input space + W1-proj MFMA + LN/GELU + GEMM2 + att2 ----
// r19: gather = explicit 2-deep software pipeline (issue batch j+1's 8 loads
// BEFORE batch j's FMAs -> loads always in flight during compute; no waste
// FMAs, unlike the r2 16-wide unroll). pk_fma kept from r18.
__global__ __launch_bounds__(512) void k_gat1_fused(
    const unsigned* __restrict__ h0,                 // [N][64] uint = [N,128] bf16
    const float4* __restrict__ als4, const float4* __restrict__ ald4, // [N]
    const int* __restrict__ cnt, const int* __restrict__ ell,
    const float* __restrict__ bias1, const float* __restrict__ g1, const float* __restrict__ b1,
    const unsigned short* __restrict__ W1t,          // [512][128] bf16
    const unsigned short* __restrict__ W2t,          // [128][512] bf16
    const float* __restrict__ att2_s, const float* __restrict__ att2_d, // [128]
    unsigned short* __restrict__ xh2b,               // [N,128] bf16
    float* __restrict__ als2, float* __restrict__ ald2) // [N]
{
  __shared__ unsigned short AggHi[16*520];           // reused as h1 tile later
  __shared__ float4 alphaW4[8][64];                  // 4 head-alphas packed per slot
  __shared__ int   srcW[8][64];
  __shared__ float scrA[8][16], scrB[8][16];
  __shared__ float scrS[8][16], scrD[8][16];
  int dstbase = blockIdx.x*16;
  int tid = threadIdx.x, wave = tid>>6, lane = tid&63;
  int kq = lane>>4, l15 = lane&15;

  // ---- Phase A: descriptors upfront (cheap), als4 staged 1-deep ----
  int degP[2], sP[2];
  float4 adP[2];
  #pragma unroll
  for (int r=0;r<2;r++){
    int d = dstbase + r*8 + wave;
    degP[r] = min(cnt[d],64);
    sP[r]   = ell[d*64 + lane];                      // unconditional
    adP[r]  = ald4[d];
  }
  #pragma unroll
  for (int r=0;r<2;r++) sP[r] = (lane < degP[r]) ? sP[r] : 0;
  float4 asCur = als4[sP[0]];

  unsigned* Hi = (unsigned*)AggHi;
  #pragma unroll
  for (int r=0; r<2; r++){
    float4 asNext;
    if (r < 1) asNext = als4[sP[1]];                 // in flight during this round
    int row = r*8 + wave;                            // 0..15
    int deg = degP[r];
    float4 ad_ = adP[r];
    float e0=0.f,e1=0.f,e2=0.f,e3=0.f;
    if (lane < deg){
      e0 = __expf(lrelu02(asCur.x+ad_.x));
      e1 = __expf(lrelu02(asCur.y+ad_.y));
      e2 = __expf(lrelu02(asCur.z+ad_.z));
      e3 = __expf(lrelu02(asCur.w+ad_.w));
    }
    srcW[wave][lane] = sP[r];
    alphaW4[wave][lane] = make_float4(e0,e1,e2,e3);
    float q0=e0,q1=e1,q2=e2,q3=e3;
    #pragma unroll
    for (int o=1;o<64;o<<=1){
      q0+=__shfl_xor(q0,o); q1+=__shfl_xor(q1,o);
      q2+=__shfl_xor(q2,o); q3+=__shfl_xor(q3,o);
    }
    float inv[4] = {1.f/q0, 1.f/q1, 1.f/q2, 1.f/q3};

    f32x2 accP0={0.f,0.f}, accP1={0.f,0.f}, accP2={0.f,0.f}, accP3={0.f,0.f};
    int degR = (deg + 7) & ~7;

    auto load8 = [&](int j, unsigned* vv){
      int4 A = *(const int4*)&srcW[wave][j];
      int4 B = *(const int4*)&srcW[wave][j+4];
      vv[0] = h0[(unsigned)A.x*64u + lane];
      vv[1] = h0[(unsigned)A.y*64u + lane];
      vv[2] = h0[(unsigned)A.z*64u + lane];
      vv[3] = h0[(unsigned)A.w*64u + lane];
      vv[4] = h0[(unsigned)B.x*64u + lane];
      vv[5] = h0[(unsigned)B.y*64u + lane];
      vv[6] = h0[(unsigned)B.z*64u + lane];
      vv[7] = h0[(unsigned)B.w*64u + lane];
    };
    auto fma8 = [&](int j, const unsigned* vv){
      #pragma unroll
      for (int i=0;i<8;i++){
        float4 a = alphaW4[wave][j+i];               // ONE b128 broadcast/edge
        f32x2 a01 = {a.x, a.y}, a23 = {a.z, a.w};
        f32x2 p   = {bflo(vv[i]), bfhi(vv[i])};
        pkfma_lo(accP0, a01, p);                     // {h0,h1} x lo
        pkfma_lo(accP1, a23, p);                     // {h2,h3} x lo
        pkfma_hi(accP2, a01, p);                     // {h0,h1} x hi
        pkfma_hi(accP3, a23, p);                     // {h2,h3} x hi
      }
    };

    unsigned v[8], vn[8];
    load8(0, v);
    int j = 0;
    for (; j+8 < degR; j+=8){
      load8(j+8, vn);                                // next batch in flight...
      fma8(j, v);                                    // ...during this compute
      #pragma unroll
      for (int i=0;i<8;i++) v[i] = vn[i];
    }
    fma8(j, v);                                      // epilogue batch

    // normalize; lane owns ch pair (2*lane, 2*lane+1) per head; bf16 pack
    Hi[row*260 + 0*64 + lane] = packbf2(accP0.x*inv[0], accP2.x*inv[0]);
    Hi[row*260 + 1*64 + lane] = packbf2(accP0.y*inv[1], accP2.y*inv[1]);
    Hi[row*260 + 2*64 + lane] = packbf2(accP1.x*inv[2], accP3.x*inv[2]);
    Hi[row*260 + 3*64 + lane] = packbf2(accP1.y*inv[3], accP3.y*inv[3]);
    if (r < 1) asCur = asNext;
  }
  __syncthreads();

  // ---- Phase B: W1 projection; wave covers cols [wave*64, wave*64+64), head = wave>>1 ----
  f32x4 acc1[4] = {};
  {
    const uint4* Hi4 = (const uint4*)AggHi;
    int h = wave>>1;
    #pragma unroll
    for (int kt=0; kt<4; kt++){
      BF8 fh;
      fh.u4 = Hi4[(size_t)l15*65 + h*16 + kt*4 + kq];
      #pragma unroll
      for (int ct=0; ct<4; ct++){
        int col = wave*64 + ct*16 + l15;
        BF8 fb; fb.u4 = *(const uint4*)&W1t[(size_t)col*128 + kt*32 + kq*8];
        acc1[ct] = __builtin_amdgcn_mfma_f32_16x16x32_bf16(fh.v, fb.v, acc1[ct], 0,0,0);
      }
    }
  }
  // epilogue: bias + LN(512) + GELU; single-pass sum+sumsq -> ONE barrier
  float vloc[4][4];
  float sum_r[4] = {0,0,0,0}, sq_r[4] = {0,0,0,0};
  #pragma unroll
  for (int ct=0; ct<4; ct++){
    int col = wave*64 + ct*16 + l15;
    float bb = bias1[col];
    #pragma unroll
    for (int r=0;r<4;r++){
      float v = acc1[ct][r] + bb;
      vloc[ct][r] = v;
      sum_r[r] += v;
      sq_r[r]  += v*v;
    }
  }
  #pragma unroll
  for (int o=1;o<16;o<<=1)
    #pragma unroll
    for (int r=0;r<4;r++){ sum_r[r] += __shfl_xor(sum_r[r], o); sq_r[r] += __shfl_xor(sq_r[r], o); }
  if (l15 == 0){
    #pragma unroll
    for (int r=0;r<4;r++){ scrA[wave][kq*4+r] = sum_r[r]; scrB[wave][kq*4+r] = sq_r[r]; }
  }
  __syncthreads();                                   // also: all MFMA A-frag reads done
  unsigned short* h1s = AggHi;                       // reuse (reads complete)
  #pragma unroll
  for (int r=0;r<4;r++){
    int m = kq*4+r;
    float s_ = 0.f, vs = 0.f;
    #pragma unroll
    for (int w=0;w<8;w++){ s_ += scrA[w][m]; vs += scrB[w][m]; }
    float mu = s_*(1.f/512.f);
    float var = vs*(1.f/512.f) - mu*mu;
    float rsv = rsqrtf(var+LN_EPS);
    #pragma unroll
    for (int ct=0; ct<4; ct++){
      int col = wave*64 + ct*16 + l15;
      float y = gelu_ex((vloc[ct][r]-mu)*rsv*g1[col] + b1[col]);
      h1s[(size_t)m*520 + col] = (unsigned short)f2bf(y);
    }
  }
  __syncthreads();

  // ---- Phase C: fused GEMM2 (wave covers out-cols [wave*16, +16)); K=512 ----
  f32x4 acc2 = {};
  const uint4* h1s4 = (const uint4*)h1s;
  int colc = wave*16 + l15;
  #pragma unroll
  for (int kt=0; kt<16; kt++){
    BF8 fa; fa.u4 = h1s4[(size_t)l15*65 + kt*4 + kq];
    BF8 fb; fb.u4 = *(const uint4*)&W2t[(size_t)colc*512 + kt*32 + kq*8];
    acc2 = __builtin_amdgcn_mfma_f32_16x16x32_bf16(fa.v, fb.v, acc2, 0,0,0);
  }
  float ps[4], pd[4];
  {
    float ws = att2_s[colc], wd = att2_d[colc];
    #pragma unroll
    for (int r2=0; r2<4; r2++){
      float vv = acc2[r2];
      xh2b[(size_t)(dstbase + kq*4 + r2)*128 + colc] = (unsigned short)f2bf(vv);
      ps[r2] = vv*ws; pd[r2] = vv*wd;
    }
  }
  #pragma unroll
  for (int o=1;o<16;o<<=1){
    #pragma unroll
    for (int r2=0;r2<4;r2++){ ps[r2]+=__shfl_xor(ps[r2],o); pd[r2]+=__shfl_xor(pd[r2],o); }
  }
  if (l15 == 0){
    #pragma unroll
    for (int r2=0;r2<4;r2++){
      scrS[wave][kq*4+r2] = ps[r2];
      scrD[wave][kq*4+r2] = pd[r2];
    }
  }
  __syncthreads();
  if (tid < 16){
    float ss = 0.f, sd = 0.f;
    #pragma unroll
    for (int w=0;w<8;w++){ ss += scrS[w][tid]; sd += scrD[w][tid]; }
    als2[dstbase+tid] = ss;
    ald2[dstbase+tid] = sd;
  }
}

// -- GAT layer 2: r19: 2-deep pipelined gather (same as gat1); den reduction
//    hoisted above the loop; pk_fma kept; Wo direct loads (L1-resident). --
__global__ __launch_bounds__(256) void k_gat2_final(
    const unsigned* __restrict__ xh,                 // [N,64] uint = [N,128] bf16
    const float* __restrict__ als, const float* __restrict__ ald, // [N]
    const int* __restrict__ cnt, const int* __restrict__ ell,
    const float* __restrict__ bias2, const float* __restrict__ g2, const float* __restrict__ b2,
    const float* __restrict__ Wo, const float* __restrict__ bo,
    float* __restrict__ out)                         // [N,32]
{
  int wave = threadIdx.x>>6, t = threadIdx.x&63;
  int d = blockIdx.x*4 + wave;
  __shared__ float alphaS[4][64];
  __shared__ int   srcS[4][64];
  __shared__ float yS[4][128];
  int deg = min(cnt[d], 64);
  int s0 = ell[d*64 + t];                            // unconditional; masked below
  float add = ald[d];
  s0 = (t < deg) ? s0 : 0;
  float lg = als[s0] + add;
  float ex = (t < deg) ? __expf(lrelu02(lg)) : 0.f;
  alphaS[wave][t] = ex;
  srcS[wave][t] = s0;

  // den reduction BEFORE the gather (independent of the loop)
  float den = ex;
  #pragma unroll
  for (int o=32;o>0;o>>=1) den += __shfl_down(den,o);
  den = __shfl(den,0);
  float inv = 1.f/den;

  f32x2 accP = {0.f, 0.f};                           // {lo-ch, hi-ch}
  int degR = (deg + 7) & ~7;

  auto load8 = [&](int j, unsigned* uu){
    int4 A = *(const int4*)&srcS[wave][j];
    int4 B = *(const int4*)&srcS[wave][j+4];
    uu[0] = xh[(unsigned)A.x*64u + t];
    uu[1] = xh[(unsigned)A.y*64u + t];
    uu[2] = xh[(unsigned)A.z*64u + t];
    uu[3] = xh[(unsigned)A.w*64u + t];
    uu[4] = xh[(unsigned)B.x*64u + t];
    uu[5] = xh[(unsigned)B.y*64u + t];
    uu[6] = xh[(unsigned)B.z*64u + t];
    uu[7] = xh[(unsigned)B.w*64u + t];
  };
  auto fma8 = [&](int j, const unsigned* uu){
    float4 aA = *(const float4*)&alphaS[wave][j];
    float4 aB = *(const float4*)&alphaS[wave][j+4];
    f32x2 aXY = {aA.x, aA.y}, aZW = {aA.z, aA.w};
    f32x2 bXY = {aB.x, aB.y}, bZW = {aB.z, aB.w};
    f32x2 v0 = {bflo(uu[0]), bfhi(uu[0])};
    f32x2 v1 = {bflo(uu[1]), bfhi(uu[1])};
    f32x2 v2 = {bflo(uu[2]), bfhi(uu[2])};
    f32x2 v3 = {bflo(uu[3]), bfhi(uu[3])};
    f32x2 v4 = {bflo(uu[4]), bfhi(uu[4])};
    f32x2 v5 = {bflo(uu[5]), bfhi(uu[5])};
    f32x2 v6 = {bflo(uu[6]), bfhi(uu[6])};
    f32x2 v7 = {bflo(uu[7]), bfhi(uu[7])};
    pkfma_lo(accP, v0, aXY);                         // += v0 * aA.x
    pkfma_hi(accP, v1, aXY);                         // += v1 * aA.y
    pkfma_lo(accP, v2, aZW);
    pkfma_hi(accP, v3, aZW);
    pkfma_lo(accP, v4, bXY);
    pkfma_hi(accP, v5, bXY);
    pkfma_lo(accP, v6, bZW);
    pkfma_hi(accP, v7, bZW);
  };

  unsigned u[8], un[8];
  load8(0, u);
  int j = 0;
  for (; j+8 < degR; j+=8){
    load8(j+8, un);                                  // next batch in flight...
    fma8(j, u);                                      // ...during this compute
    #pragma unroll
    for (int i=0;i<8;i++) u[i] = un[i];
  }
  fma8(j, u);                                        // epilogue batch

  float2 bb = ((const float2*)bias2)[t];
  float v0 = accP.x*inv + bb.x;
  float v1 = accP.y*inv + bb.y;

  // LN(128) — single merged (sum, sumsq) tree
  float s1 = v0+v1, q = v0*v0+v1*v1;
  #pragma unroll
  for (int o=32;o>0;o>>=1){ s1 += __shfl_down(s1,o); q += __shfl_down(q,o); }
  s1 = __shfl(s1,0); q = __shfl(q,0);
  float mu = s1*(1.f/128.f);
  float var = q*(1.f/128.f) - mu*mu;
  float rs = rsqrtf(var+LN_EPS);
  float d0=v0-mu, d1=v1-mu;
  float2 gg = ((const float2*)g2)[t];
  float2 b4 = ((const float2*)b2)[t];
  float y0 = gelu_ex(d0*rs*gg.x+b4.x);
  float y1 = gelu_ex(d1*rs*gg.y+b4.y);

  // projection (128->32): stage y in wave-private LDS, broadcast-read back.
  ((float2*)&yS[wave][0])[t] = make_float2(y0,y1);   // lane t owns ch 2t,2t+1
  int half = t>>5, c = t&31;
  const float4* y4 = (const float4*)&yS[wave][half*64];
  f32x2 partP = {0.f, 0.f};                          // {even-ch, odd-ch} partials
  #pragma unroll
  for (int k=0;k<16;k++){
    float4 yv = y4[k];                               // broadcast per half-wave
    int ch = half*64 + k*4;
    f32x2 w01 = {Wo[(ch+0)*32 + c], Wo[(ch+1)*32 + c]};
    f32x2 w23 = {Wo[(ch+2)*32 + c], Wo[(ch+3)*32 + c]};
    f32x2 yxy = {yv.x, yv.y}, yzw = {yv.z, yv.w};
    pkfma(partP, yxy, w01);
    pkfma(partP, yzw, w23);
  }
  float part = partP.x + partP.y;
  part += __shfl_down(part, 32);                     // lanes 0..31 hold full dot
  float logit = part + bo[c];

  // log_softmax over 32 (lanes 0..31)
  float mx = logit;
  #pragma unroll
  for (int o=16;o>0;o>>=1) mx = fmaxf(mx, __shfl_xor(mx,o));
  float se = __expf(logit-mx);
  #pragma unroll
  for (int o=16;o>0;o>>=1) se += __shfl_xor(se,o);
  float lse = mx + __logf(se);
  if (t < 32) out[(size_t)d*32+t] = logit - lse;
}

extern "C" void kernel_launch(void* const* d_in, const int* in_sizes, int n_in,
                              void* d_out, int out_size, void* d_ws, size_t ws_size,
                              hipStream_t stream) {
  const float* x      = (const float*)d_in[0];
  const int*   ei     = (const int*)d_in[1];
  const float* g_in   = (const float*)d_in[2];
  const float* b_in   = (const float*)d_in[3];
  const float* W1     = (const float*)d_in[4];
  const float* att1_s = (const float*)d_in[5];
  const float* att1_d = (const float*)d_in[6];
  const float* bias1  = (const float*)d_in[7];
  const float* g1     = (const float*)d_in[8];
  const float* b1     = (const float*)d_in[9];
  const float* W2     = (const float*)d_in[10];
  const float* att2_s = (const float*)d_in[11];
  const float* att2_d = (const float*)d_in[12];
  const float* bias2  = (const float*)d_in[13];
  const float* g2     = (const float*)d_in[14];
  const float* b2     = (const float*)d_in[15];
  const float* Wo     = (const float*)d_in[16];
  const float* bo     = (const float*)d_in[17];
  float* out = (float*)d_out;

  char* ws = (char*)d_ws;
  size_t off = 0;
  auto alloc = [&](size_t bytes)->char*{
    char* p = ws + off; off += (bytes + 255) & ~(size_t)255; return p;
  };
  unsigned* h0b   = (unsigned*)alloc((size_t)N_NODES*128*2);       // LN(x) bf16 table
  unsigned short* xh2b = (unsigned short*)alloc((size_t)N_NODES*128*2); // fused GEMM2 out bf16
  float*    als1  = (float*)alloc((size_t)N_NODES*4*4);
  float*    ald1  = (float*)alloc((size_t)N_NODES*4*4);
  float*    als2  = (float*)alloc((size_t)N_NODES*4);
  float*    ald2  = (float*)alloc((size_t)N_NODES*4);
  int*      cnt   = (int*)alloc((size_t)N_NODES*4);
  int*      ell   = (int*)alloc((size_t)N_NODES*64*4);             // ELL adjacency
  unsigned short* W1t = (unsigned short*)alloc((size_t)512*128*2); // [512][128] bf16
  unsigned short* W2t = (unsigned short*)alloc((size_t)128*512*2); // [128][512] bf16
  float*    wtil  = (float*)alloc((size_t)8*128*4);                // fused logit vecs

  // 1. weight transposes + parallel w~ + zero cnt
  k_prep<<<TB1 + TB2 + WTB + ZCB,256,0,stream>>>(W1, W2, att1_s, att1_d,
                                                 W1t, W2t, wtil, cnt);
  // 2. ELL build + input LN + fp32 att1 logits
  k_build_mega<<<EBL + LNB,256,0,stream>>>(ei, cnt, ell, x, g_in, b_in, wtil,
                                           h0b, (float4*)als1, (float4*)ald1);
  // 3. GAT1 in input space + W1-proj MFMA + LN/GELU + fused GEMM2 + att2 logits
  k_gat1_fused<<<N_NODES/16,512,0,stream>>>(h0b,
      (const float4*)als1, (const float4*)ald1, cnt, ell,
      bias1, g1, b1, W1t, W2t, att2_s, att2_d, xh2b, als2, ald2);
  // 4. GAT layer 2 + Wo projection + log_softmax
  k_gat2_final<<<N_NODES/4,256,0,stream>>>((const unsigned*)xh2b, als2, ald2,
      cnt, ell, bias2, g2, b2, Wo, bo, out);
}

// Round 6
// 209.809 us; speedup vs baseline: 1.0686x; 1.0090x over previous
//
#include <hip/hip_runtime.h>
#include <hip/hip_bf16.h>
#include <math.h>

static constexpr int N_NODES = 20000;
static constexpr int N_EDGES = 320000;
static constexpr int ETOT    = N_EDGES + N_NODES;   // edges + self loops
static constexpr float LN_EPS = 1e-5f;

__device__ __forceinline__ float lrelu02(float x){ return x > 0.f ? x : 0.2f*x; }
__device__ __forceinline__ float gelu_ex(float x){ return 0.5f*x*(1.f+erff(x*0.70710678118654752f)); }
__device__ __forceinline__ float bflo(unsigned u){ return __uint_as_float(u<<16); }
__device__ __forceinline__ float bfhi(unsigned u){ return __uint_as_float(u & 0xffff0000u); }
__device__ __forceinline__ unsigned f2bf(float f){           // RNE fp32->bf16
  unsigned u = __float_as_uint(f);
  return (u + 0x7fffu + ((u>>16)&1u)) >> 16;
}
__device__ __forceinline__ unsigned packbf2(float a, float b){ return f2bf(a) | (f2bf(b)<<16); }

typedef __attribute__((ext_vector_type(8))) short bf16x8;
typedef __attribute__((ext_vector_type(4))) float f32x4;
typedef __attribute__((ext_vector_type(2))) float f32x2;
union BF8 { unsigned short us[8]; bf16x8 v; uint4 u4; };

// ---- packed f32 FMA (VOP3P). d.lo = a.lo*b.lo + c.lo etc.
__device__ __forceinline__ void pkfma(f32x2& c, f32x2 a, f32x2 b){
  asm("v_pk_fma_f32 %0, %1, %2, %0" : "+v"(c) : "v"(a), "v"(b));
}
__device__ __forceinline__ void pkfma_lo(f32x2& c, f32x2 a, f32x2 b){
  asm("v_pk_fma_f32 %0, %1, %2, %0 op_sel_hi:[1,0,1]" : "+v"(c) : "v"(a), "v"(b));
}
__device__ __forceinline__ void pkfma_hi(f32x2& c, f32x2 a, f32x2 b){
  asm("v_pk_fma_f32 %0, %1, %2, %0 op_sel:[0,1,0] op_sel_hi:[1,1,1]" : "+v"(c) : "v"(a), "v"(b));
}

// ---- prep: weight transposes + PARALLEL w~ + zero cnt ----
static constexpr int TB1 = 512*128/256;             // 256 blocks W1t
static constexpr int TB2 = 512*128/256;             // 256 blocks W2t
static constexpr int WTB = 128;                     // 128 blocks wtil (8 outs ea, 32 thr/out)
static constexpr int ZCB = (N_NODES + 255)/256;     // 79 blocks zero-cnt
__global__ __launch_bounds__(256) void k_prep(
    const float* __restrict__ W1, const float* __restrict__ W2,
    const float* __restrict__ att1_s, const float* __restrict__ att1_d,
    unsigned short* __restrict__ W1t, unsigned short* __restrict__ W2t,
    float* __restrict__ wtil, int* __restrict__ cnt) {
  int b = blockIdx.x, tid = threadIdx.x;
  if (b < TB1){                                     // W1t[n][k]=bf16(W1[k][n]) K=128,N=512
    int idx = b*256 + tid;
    int n = idx >> 7, k = idx & 127;
    W1t[idx] = (unsigned short)f2bf(W1[(size_t)k*512 + n]);
    return;
  }
  if (b < TB1 + TB2){                               // W2t[n][k]=bf16(W2[k][n]) K=512,N=128
    int idx = (b-TB1)*256 + tid;
    int n = idx >> 9, k = idx & 511;
    W2t[idx] = (unsigned short)f2bf(W2[(size_t)k*128 + n]);
    return;
  }
  if (b < TB1 + TB2 + WTB){
    // wtil[v*128+k] = sum_c W1[k, (v&3)*128+c]*att{s|d}[(v&3),c]; 32 thr/output
    int o = (b-TB1-TB2)*8 + (tid>>5);               // 0..1023
    int c32 = tid & 31;
    int v = o >> 7, k = o & 127, h = v & 3;
    const float* av = (v < 4) ? (att1_s + h*128) : (att1_d + h*128);
    const float* wr = W1 + (size_t)k*512 + h*128;
    float p = wr[c32]*av[c32] + wr[c32+32]*av[c32+32]
            + wr[c32+64]*av[c32+64] + wr[c32+96]*av[c32+96];
    #pragma unroll
    for (int o2=1;o2<32;o2<<=1) p += __shfl_xor(p, o2);
    if (c32 == 0) wtil[o] = p;
    return;
  }
  int idx = (b - TB1 - TB2 - WTB)*256 + tid;        // zero cnt
  if (idx < N_NODES) cnt[idx] = 0;
}

// ---- mega kernel: ELL build (atomic slots) + input LN + fp32 att1 logits ----
static constexpr int EBL = (ETOT + 255)/256;        // 1329 edge blocks
static constexpr int LNB = N_NODES/4;               // 5000 LN blocks (4 rows ea)
__global__ __launch_bounds__(256) void k_build_mega(
    const int* __restrict__ ei, int* __restrict__ cnt, int* __restrict__ ell,
    const float* __restrict__ x, const float* __restrict__ g_in,
    const float* __restrict__ b_in, const float* __restrict__ wtil,
    unsigned* __restrict__ h0b, float4* __restrict__ als4, float4* __restrict__ ald4) {
  int b = blockIdx.x, tid = threadIdx.x;
  if (b < EBL){                                     // ELL scatter (deg<=64 w.h.p.)
    int e = b*256 + tid;
    int s, d;
    if (e < N_EDGES){ s = ei[e]; d = ei[N_EDGES+e]; }
    else if (e < ETOT){ s = e - N_EDGES; d = s; }
    else return;
    int pos = atomicAdd(&cnt[d], 1);
    if (pos < 64) ell[d*64 + pos] = s;
    return;
  }
  // LN over 128-ch rows -> bf16 h0b; logits als/ald = h0 . w~ (fp32 exact)
  int row = (b - EBL)*4 + (tid>>6);
  int t = tid & 63;
  float2 v = ((const float2*)(x + (size_t)row*128))[t];
  float s = v.x + v.y;
  float q = v.x*v.x + v.y*v.y;
  #pragma unroll
  for (int o=32;o>0;o>>=1){ s += __shfl_down(s,o); q += __shfl_down(q,o); }
  s = __shfl(s,0); q = __shfl(q,0);
  float mu = s*(1.f/128.f);
  float var = q*(1.f/128.f) - mu*mu;
  float rs = rsqrtf(var+LN_EPS);
  float d0 = v.x-mu, d1 = v.y-mu;
  float2 gg = ((const float2*)g_in)[t];
  float2 bb = ((const float2*)b_in)[t];
  float y0 = d0*rs*gg.x+bb.x;
  float y1 = d1*rs*gg.y+bb.y;
  h0b[(size_t)row*64 + t] = packbf2(y0,y1);
  float ps[4], pd[4];
  #pragma unroll
  for (int h=0;h<4;h++){
    float2 ws = ((const float2*)(wtil + h*128))[t];
    float2 wd = ((const float2*)(wtil + (4+h)*128))[t];
    ps[h] = y0*ws.x + y1*ws.y;
    pd[h] = y0*wd.x + y1*wd.y;
  }
  #pragma unroll
  for (int o=1;o<64;o<<=1){
    #pragma unroll
    for (int h=0;h<4;h++){ ps[h]+=__shfl_xor(ps[h],o); pd[h]+=__shfl_xor(pd[h],o); }
  }
  if (t==0){
    als4[row] = make_float4(ps[0],ps[1],ps[2],ps[3]);
    ald4[row] = make_float4(pd[0],pd[1],pd[2],pd[3]);
  }
}

// ---- r20: GAT1 SPLIT. Part 1: aggregation only. 1 wave = 1 dst, 4 waves/block,
// ZERO barriers -> degree imbalance no longer couples waves; waves retire
// independently. Output agg[N][512]bf16 (uint pairs), coalesced 256B stores. ----
__global__ __launch_bounds__(256) void k_gat1_agg(
    const unsigned* __restrict__ h0,                 // [N][64] uint = [N,128] bf16
    const float4* __restrict__ als4, const float4* __restrict__ ald4, // [N]
    const int* __restrict__ cnt, const int* __restrict__ ell,
    unsigned* __restrict__ agg)                      // [N][256] uint = [N,512] bf16
{
  int wave = threadIdx.x>>6, lane = threadIdx.x&63;
  int d = blockIdx.x*4 + wave;
  __shared__ float4 alphaW4[4][64];
  __shared__ int   srcW[4][64];

  int deg = min(cnt[d],64);
  int s0 = ell[d*64 + lane];                         // unconditional; masked below
  float4 ad_ = ald4[d];
  s0 = (lane < deg) ? s0 : 0;
  float4 as_ = als4[s0];
  float e0=0.f,e1=0.f,e2=0.f,e3=0.f;
  if (lane < deg){
    e0 = __expf(lrelu02(as_.x+ad_.x));
    e1 = __expf(lrelu02(as_.y+ad_.y));
    e2 = __expf(lrelu02(as_.z+ad_.z));
    e3 = __expf(lrelu02(as_.w+ad_.w));
  }
  srcW[wave][lane] = s0;
  alphaW4[wave][lane] = make_float4(e0,e1,e2,e3);
  float q0=e0,q1=e1,q2=e2,q3=e3;
  #pragma unroll
  for (int o=1;o<64;o<<=1){
    q0+=__shfl_xor(q0,o); q1+=__shfl_xor(q1,o);
    q2+=__shfl_xor(q2,o); q3+=__shfl_xor(q3,o);
  }
  float inv[4] = {1.f/q0, 1.f/q1, 1.f/q2, 1.f/q3};

  f32x2 accP0={0.f,0.f}, accP1={0.f,0.f}, accP2={0.f,0.f}, accP3={0.f,0.f};
  int degR = (deg + 7) & ~7;

  auto load8 = [&](int j, unsigned* vv){
    int4 A = *(const int4*)&srcW[wave][j];
    int4 B = *(const int4*)&srcW[wave][j+4];
    vv[0] = h0[(unsigned)A.x*64u + lane];
    vv[1] = h0[(unsigned)A.y*64u + lane];
    vv[2] = h0[(unsigned)A.z*64u + lane];
    vv[3] = h0[(unsigned)A.w*64u + lane];
    vv[4] = h0[(unsigned)B.x*64u + lane];
    vv[5] = h0[(unsigned)B.y*64u + lane];
    vv[6] = h0[(unsigned)B.z*64u + lane];
    vv[7] = h0[(unsigned)B.w*64u + lane];
  };
  auto fma8 = [&](int j, const unsigned* vv){
    #pragma unroll
    for (int i=0;i<8;i++){
      float4 a = alphaW4[wave][j+i];                 // ONE b128 broadcast/edge
      f32x2 a01 = {a.x, a.y}, a23 = {a.z, a.w};
      f32x2 p   = {bflo(vv[i]), bfhi(vv[i])};
      pkfma_lo(accP0, a01, p);                       // {h0,h1} x lo
      pkfma_lo(accP1, a23, p);                       // {h2,h3} x lo
      pkfma_hi(accP2, a01, p);                       // {h0,h1} x hi
      pkfma_hi(accP3, a23, p);                       // {h2,h3} x hi
    }
  };

  unsigned v[8], vn[8];
  load8(0, v);
  int j = 0;
  for (; j+8 < degR; j+=8){
    load8(j+8, vn);                                  // next batch in flight...
    fma8(j, v);                                      // ...during this compute
    #pragma unroll
    for (int i=0;i<8;i++) v[i] = vn[i];
  }
  fma8(j, v);                                        // epilogue batch

  // normalize; lane owns ch pair (2*lane, 2*lane+1) per head; bf16 pack
  unsigned* arow = agg + (size_t)d*256;
  arow[0*64 + lane] = packbf2(accP0.x*inv[0], accP2.x*inv[0]);
  arow[1*64 + lane] = packbf2(accP0.y*inv[1], accP2.y*inv[1]);
  arow[2*64 + lane] = packbf2(accP1.x*inv[2], accP3.x*inv[2]);
  arow[3*64 + lane] = packbf2(accP1.y*inv[3], accP3.y*inv[3]);
}

// ---- r20: GAT1 Part 2: W1-proj MFMA + LN(512)/GELU + GEMM2 + att2 logits.
// Identical to the old Phases B/C but A-fragments come from global agg.
// Uniform compute, no data-dependent imbalance. 16 rows/block, 512 thr. ----
__global__ __launch_bounds__(512) void k_gat1_mlp(
    const unsigned* __restrict__ agg,                // [N][256] uint
    const float* __restrict__ bias1, const float* __restrict__ g1, const float* __restrict__ b1,
    const unsigned short* __restrict__ W1t,          // [512][128] bf16
    const unsigned short* __restrict__ W2t,          // [128][512] bf16
    const float* __restrict__ att2_s, const float* __restrict__ att2_d, // [128]
    unsigned short* __restrict__ xh2b,               // [N,128] bf16
    float* __restrict__ als2, float* __restrict__ ald2) // [N]
{
  __shared__ unsigned short h1s[16*520];
  __shared__ float scrA[8][16], scrB[8][16];
  __shared__ float scrS[8][16], scrD[8][16];
  int dstbase = blockIdx.x*16;
  int tid = threadIdx.x, wave = tid>>6, lane = tid&63;
  int kq = lane>>4, l15 = lane&15;

  // ---- Phase B: W1 projection; wave covers cols [wave*64,+64), head = wave>>1 ----
  f32x4 acc1[4] = {};
  {
    const uint4* Agg4 = (const uint4*)agg;           // row stride 64 uint4
    int h = wave>>1;
    #pragma unroll
    for (int kt=0; kt<4; kt++){
      BF8 fh;
      fh.u4 = Agg4[(size_t)(dstbase + l15)*64 + h*16 + kt*4 + kq];
      #pragma unroll
      for (int ct=0; ct<4; ct++){
        int col = wave*64 + ct*16 + l15;
        BF8 fb; fb.u4 = *(const uint4*)&W1t[(size_t)col*128 + kt*32 + kq*8];
        acc1[ct] = __builtin_amdgcn_mfma_f32_16x16x32_bf16(fh.v, fb.v, acc1[ct], 0,0,0);
      }
    }
  }
  // epilogue: bias + LN(512) + GELU; single-pass sum+sumsq -> ONE barrier
  float vloc[4][4];
  float sum_r[4] = {0,0,0,0}, sq_r[4] = {0,0,0,0};
  #pragma unroll
  for (int ct=0; ct<4; ct++){
    int col = wave*64 + ct*16 + l15;
    float bb = bias1[col];
    #pragma unroll
    for (int r=0;r<4;r++){
      float v = acc1[ct][r] + bb;
      vloc[ct][r] = v;
      sum_r[r] += v;
      sq_r[r]  += v*v;
    }
  }
  #pragma unroll
  for (int o=1;o<16;o<<=1)
    #pragma unroll
    for (int r=0;r<4;r++){ sum_r[r] += __shfl_xor(sum_r[r], o); sq_r[r] += __shfl_xor(sq_r[r], o); }
  if (l15 == 0){
    #pragma unroll
    for (int r=0;r<4;r++){ scrA[wave][kq*4+r] = sum_r[r]; scrB[wave][kq*4+r] = sq_r[r]; }
  }
  __syncthreads();
  #pragma unroll
  for (int r=0;r<4;r++){
    int m = kq*4+r;
    float s_ = 0.f, vs = 0.f;
    #pragma unroll
    for (int w=0;w<8;w++){ s_ += scrA[w][m]; vs += scrB[w][m]; }
    float mu = s_*(1.f/512.f);
    float var = vs*(1.f/512.f) - mu*mu;
    float rsv = rsqrtf(var+LN_EPS);
    #pragma unroll
    for (int ct=0; ct<4; ct++){
      int col = wave*64 + ct*16 + l15;
      float y = gelu_ex((vloc[ct][r]-mu)*rsv*g1[col] + b1[col]);
      h1s[(size_t)m*520 + col] = (unsigned short)f2bf(y);
    }
  }
  __syncthreads();

  // ---- Phase C: fused GEMM2 (wave covers out-cols [wave*16, +16)); K=512 ----
  f32x4 acc2 = {};
  const uint4* h1s4 = (const uint4*)h1s;
  int colc = wave*16 + l15;
  #pragma unroll
  for (int kt=0; kt<16; kt++){
    BF8 fa; fa.u4 = h1s4[(size_t)l15*65 + kt*4 + kq];
    BF8 fb; fb.u4 = *(const uint4*)&W2t[(size_t)colc*512 + kt*32 + kq*8];
    acc2 = __builtin_amdgcn_mfma_f32_16x16x32_bf16(fa.v, fb.v, acc2, 0,0,0);
  }
  float ps[4], pd[4];
  {
    float ws = att2_s[colc], wd = att2_d[colc];
    #pragma unroll
    for (int r2=0; r2<4; r2++){
      float vv = acc2[r2];
      xh2b[(size_t)(dstbase + kq*4 + r2)*128 + colc] = (unsigned short)f2bf(vv);
      ps[r2] = vv*ws; pd[r2] = vv*wd;
    }
  }
  #pragma unroll
  for (int o=1;o<16;o<<=1){
    #pragma unroll
    for (int r2=0;r2<4;r2++){ ps[r2]+=__shfl_xor(ps[r2],o); pd[r2]+=__shfl_xor(pd[r2],o); }
  }
  if (l15 == 0){
    #pragma unroll
    for (int r2=0;r2<4;r2++){
      scrS[wave][kq*4+r2] = ps[r2];
      scrD[wave][kq*4+r2] = pd[r2];
    }
  }
  __syncthreads();
  if (tid < 16){
    float ss = 0.f, sd = 0.f;
    #pragma unroll
    for (int w=0;w<8;w++){ ss += scrS[w][tid]; sd += scrD[w][tid]; }
    als2[dstbase+tid] = ss;
    ald2[dstbase+tid] = sd;
  }
}

// -- GAT layer 2: unchanged from r19 (2-deep pipelined gather, den hoisted,
//    pk_fma, LDS-broadcast projection, Wo direct loads). --
__global__ __launch_bounds__(256) void k_gat2_final(
    const unsigned* __restrict__ xh,                 // [N,64] uint = [N,128] bf16
    const float* __restrict__ als, const float* __restrict__ ald, // [N]
    const int* __restrict__ cnt, const int* __restrict__ ell,
    const float* __restrict__ bias2, const float* __restrict__ g2, const float* __restrict__ b2,
    const float* __restrict__ Wo, const float* __restrict__ bo,
    float* __restrict__ out)                         // [N,32]
{
  int wave = threadIdx.x>>6, t = threadIdx.x&63;
  int d = blockIdx.x*4 + wave;
  __shared__ float alphaS[4][64];
  __shared__ int   srcS[4][64];
  __shared__ float yS[4][128];
  int deg = min(cnt[d], 64);
  int s0 = ell[d*64 + t];                            // unconditional; masked below
  float add = ald[d];
  s0 = (t < deg) ? s0 : 0;
  float lg = als[s0] + add;
  float ex = (t < deg) ? __expf(lrelu02(lg)) : 0.f;
  alphaS[wave][t] = ex;
  srcS[wave][t] = s0;

  // den reduction BEFORE the gather (independent of the loop)
  float den = ex;
  #pragma unroll
  for (int o=32;o>0;o>>=1) den += __shfl_down(den,o);
  den = __shfl(den,0);
  float inv = 1.f/den;

  f32x2 accP = {0.f, 0.f};                           // {lo-ch, hi-ch}
  int degR = (deg + 7) & ~7;

  auto load8 = [&](int j, unsigned* uu){
    int4 A = *(const int4*)&srcS[wave][j];
    int4 B = *(const int4*)&srcS[wave][j+4];
    uu[0] = xh[(unsigned)A.x*64u + t];
    uu[1] = xh[(unsigned)A.y*64u + t];
    uu[2] = xh[(unsigned)A.z*64u + t];
    uu[3] = xh[(unsigned)A.w*64u + t];
    uu[4] = xh[(unsigned)B.x*64u + t];
    uu[5] = xh[(unsigned)B.y*64u + t];
    uu[6] = xh[(unsigned)B.z*64u + t];
    uu[7] = xh[(unsigned)B.w*64u + t];
  };
  auto fma8 = [&](int j, const unsigned* uu){
    float4 aA = *(const float4*)&alphaS[wave][j];
    float4 aB = *(const float4*)&alphaS[wave][j+4];
    f32x2 aXY = {aA.x, aA.y}, aZW = {aA.z, aA.w};
    f32x2 bXY = {aB.x, aB.y}, bZW = {aB.z, aB.w};
    f32x2 v0 = {bflo(uu[0]), bfhi(uu[0])};
    f32x2 v1 = {bflo(uu[1]), bfhi(uu[1])};
    f32x2 v2 = {bflo(uu[2]), bfhi(uu[2])};
    f32x2 v3 = {bflo(uu[3]), bfhi(uu[3])};
    f32x2 v4 = {bflo(uu[4]), bfhi(uu[4])};
    f32x2 v5 = {bflo(uu[5]), bfhi(uu[5])};
    f32x2 v6 = {bflo(uu[6]), bfhi(uu[6])};
    f32x2 v7 = {bflo(uu[7]), bfhi(uu[7])};
    pkfma_lo(accP, v0, aXY);                         // += v0 * aA.x
    pkfma_hi(accP, v1, aXY);                         // += v1 * aA.y
    pkfma_lo(accP, v2, aZW);
    pkfma_hi(accP, v3, aZW);
    pkfma_lo(accP, v4, bXY);
    pkfma_hi(accP, v5, bXY);
    pkfma_lo(accP, v6, bZW);
    pkfma_hi(accP, v7, bZW);
  };

  unsigned u[8], un[8];
  load8(0, u);
  int j = 0;
  for (; j+8 < degR; j+=8){
    load8(j+8, un);                                  // next batch in flight...
    fma8(j, u);                                      // ...during this compute
    #pragma unroll
    for (int i=0;i<8;i++) u[i] = un[i];
  }
  fma8(j, u);                                        // epilogue batch

  float2 bb = ((const float2*)bias2)[t];
  float v0 = accP.x*inv + bb.x;
  float v1 = accP.y*inv + bb.y;

  // LN(128) — single merged (sum, sumsq) tree
  float s1 = v0+v1, q = v0*v0+v1*v1;
  #pragma unroll
  for (int o=32;o>0;o>>=1){ s1 += __shfl_down(s1,o); q += __shfl_down(q,o); }
  s1 = __shfl(s1,0); q = __shfl(q,0);
  float mu = s1*(1.f/128.f);
  float var = q*(1.f/128.f) - mu*mu;
  float rs = rsqrtf(var+LN_EPS);
  float d0=v0-mu, d1=v1-mu;
  float2 gg = ((const float2*)g2)[t];
  float2 b4 = ((const float2*)b2)[t];
  float y0 = gelu_ex(d0*rs*gg.x+b4.x);
  float y1 = gelu_ex(d1*rs*gg.y+b4.y);

  // projection (128->32): stage y in wave-private LDS, broadcast-read back.
  ((float2*)&yS[wave][0])[t] = make_float2(y0,y1);   // lane t owns ch 2t,2t+1
  int half = t>>5, c = t&31;
  const float4* y4 = (const float4*)&yS[wave][half*64];
  f32x2 partP = {0.f, 0.f};                          // {even-ch, odd-ch} partials
  #pragma unroll
  for (int k=0;k<16;k++){
    float4 yv = y4[k];                               // broadcast per half-wave
    int ch = half*64 + k*4;
    f32x2 w01 = {Wo[(ch+0)*32 + c], Wo[(ch+1)*32 + c]};
    f32x2 w23 = {Wo[(ch+2)*32 + c], Wo[(ch+3)*32 + c]};
    f32x2 yxy = {yv.x, yv.y}, yzw = {yv.z, yv.w};
    pkfma(partP, yxy, w01);
    pkfma(partP, yzw, w23);
  }
  float part = partP.x + partP.y;
  part += __shfl_down(part, 32);                     // lanes 0..31 hold full dot
  float logit = part + bo[c];

  // log_softmax over 32 (lanes 0..31)
  float mx = logit;
  #pragma unroll
  for (int o=16;o>0;o>>=1) mx = fmaxf(mx, __shfl_xor(mx,o));
  float se = __expf(logit-mx);
  #pragma unroll
  for (int o=16;o>0;o>>=1) se += __shfl_xor(se,o);
  float lse = mx + __logf(se);
  if (t < 32) out[(size_t)d*32+t] = logit - lse;
}

extern "C" void kernel_launch(void* const* d_in, const int* in_sizes, int n_in,
                              void* d_out, int out_size, void* d_ws, size_t ws_size,
                              hipStream_t stream) {
  const float* x      = (const float*)d_in[0];
  const int*   ei     = (const int*)d_in[1];
  const float* g_in   = (const float*)d_in[2];
  const float* b_in   = (const float*)d_in[3];
  const float* W1     = (const float*)d_in[4];
  const float* att1_s = (const float*)d_in[5];
  const float* att1_d = (const float*)d_in[6];
  const float* bias1  = (const float*)d_in[7];
  const float* g1     = (const float*)d_in[8];
  const float* b1     = (const float*)d_in[9];
  const float* W2     = (const float*)d_in[10];
  const float* att2_s = (const float*)d_in[11];
  const float* att2_d = (const float*)d_in[12];
  const float* bias2  = (const float*)d_in[13];
  const float* g2     = (const float*)d_in[14];
  const float* b2     = (const float*)d_in[15];
  const float* Wo     = (const float*)d_in[16];
  const float* bo     = (const float*)d_in[17];
  float* out = (float*)d_out;

  char* ws = (char*)d_ws;
  size_t off = 0;
  auto alloc = [&](size_t bytes)->char*{
    char* p = ws + off; off += (bytes + 255) & ~(size_t)255; return p;
  };
  unsigned* h0b   = (unsigned*)alloc((size_t)N_NODES*128*2);       // LN(x) bf16 table
  unsigned short* xh2b = (unsigned short*)alloc((size_t)N_NODES*128*2); // fused GEMM2 out bf16
  unsigned* aggb  = (unsigned*)alloc((size_t)N_NODES*512*2);       // GAT1 agg bf16 [N][512]
  float*    als1  = (float*)alloc((size_t)N_NODES*4*4);
  float*    ald1  = (float*)alloc((size_t)N_NODES*4*4);
  float*    als2  = (float*)alloc((size_t)N_NODES*4);
  float*    ald2  = (float*)alloc((size_t)N_NODES*4);
  int*      cnt   = (int*)alloc((size_t)N_NODES*4);
  int*      ell   = (int*)alloc((size_t)N_NODES*64*4);             // ELL adjacency
  unsigned short* W1t = (unsigned short*)alloc((size_t)512*128*2); // [512][128] bf16
  unsigned short* W2t = (unsigned short*)alloc((size_t)128*512*2); // [128][512] bf16
  float*    wtil  = (float*)alloc((size_t)8*128*4);                // fused logit vecs

  // 1. weight transposes + parallel w~ + zero cnt
  k_prep<<<TB1 + TB2 + WTB + ZCB,256,0,stream>>>(W1, W2, att1_s, att1_d,
                                                 W1t, W2t, wtil, cnt);
  // 2. ELL build + input LN + fp32 att1 logits
  k_build_mega<<<EBL + LNB,256,0,stream>>>(ei, cnt, ell, x, g_in, b_in, wtil,
                                           h0b, (float4*)als1, (float4*)ald1);
  // 3a. GAT1 aggregation (barrier-free, 1 wave/dst)
  k_gat1_agg<<<N_NODES/4,256,0,stream>>>(h0b,
      (const float4*)als1, (const float4*)ald1, cnt, ell, aggb);
  // 3b. GAT1 MLP: W1-proj MFMA + LN/GELU + GEMM2 + att2 logits
  k_gat1_mlp<<<N_NODES/16,512,0,stream>>>(aggb,
      bias1, g1, b1, W1t, W2t, att2_s, att2_d, xh2b, als2, ald2);
  // 4. GAT layer 2 + Wo projection + log_softmax
  k_gat2_final<<<N_NODES/4,256,0,stream>>>((const unsigned*)xh2b, als2, ald2,
      cnt, ell, bias2, g2, b2, Wo, bo, out);
}

// Round 7
// 186.605 us; speedup vs baseline: 1.2014x; 1.1243x over previous
//
#include <hip/hip_runtime.h>
#include <hip/hip_bf16.h>
#include <math.h>

static constexpr int N_NODES = 20000;
static constexpr int N_EDGES = 320000;
static constexpr int ETOT    = N_EDGES + N_NODES;   // edges + self loops
static constexpr float LN_EPS = 1e-5f;

__device__ __forceinline__ float lrelu02(float x){ return x > 0.f ? x : 0.2f*x; }
__device__ __forceinline__ float gelu_ex(float x){ return 0.5f*x*(1.f+erff(x*0.70710678118654752f)); }
__device__ __forceinline__ float bflo(unsigned u){ return __uint_as_float(u<<16); }
__device__ __forceinline__ float bfhi(unsigned u){ return __uint_as_float(u & 0xffff0000u); }
__device__ __forceinline__ unsigned f2bf(float f){           // RNE fp32->bf16
  unsigned u = __float_as_uint(f);
  return (u + 0x7fffu + ((u>>16)&1u)) >> 16;
}
__device__ __forceinline__ unsigned packbf2(float a, float b){ return f2bf(a) | (f2bf(b)<<16); }

typedef __attribute__((ext_vector_type(8))) short bf16x8;
typedef __attribute__((ext_vector_type(4))) float f32x4;
typedef __attribute__((ext_vector_type(2))) float f32x2;
union BF8 { unsigned short us[8]; bf16x8 v; uint4 u4; };

// ---- packed f32 FMA (VOP3P). d.lo = a.lo*b.lo + c.lo etc.
__device__ __forceinline__ void pkfma(f32x2& c, f32x2 a, f32x2 b){
  asm("v_pk_fma_f32 %0, %1, %2, %0" : "+v"(c) : "v"(a), "v"(b));
}
__device__ __forceinline__ void pkfma_lo(f32x2& c, f32x2 a, f32x2 b){
  asm("v_pk_fma_f32 %0, %1, %2, %0 op_sel_hi:[1,0,1]" : "+v"(c) : "v"(a), "v"(b));
}
__device__ __forceinline__ void pkfma_hi(f32x2& c, f32x2 a, f32x2 b){
  asm("v_pk_fma_f32 %0, %1, %2, %0 op_sel:[0,1,0] op_sel_hi:[1,1,1]" : "+v"(c) : "v"(a), "v"(b));
}

// ---- prep: FRAGMENT-MAJOR weight packs + PARALLEL w~ + zero cnt ----
// r21: W1f/W2f store, at flat addr ((tile,kt,kq,l15)), exactly the 16B chunk
// MFMA lane (kq,l15) consumes -> every B-frag wave-load is contiguous 1KB
// (was: lane stride 256B/1KB = 64-line divergence per load, TA-serialized).
static constexpr int TB1 = 512*128/256;             // 256 blocks W1f
static constexpr int TB2 = 512*128/256;             // 256 blocks W2f
static constexpr int WTB = 128;                     // 128 blocks wtil (8 outs ea, 32 thr/out)
static constexpr int ZCB = (N_NODES + 255)/256;     // 79 blocks zero-cnt
__global__ __launch_bounds__(256) void k_prep(
    const float* __restrict__ W1, const float* __restrict__ W2,
    const float* __restrict__ att1_s, const float* __restrict__ att1_d,
    unsigned short* __restrict__ W1f, unsigned short* __restrict__ W2f,
    float* __restrict__ wtil, int* __restrict__ cnt) {
  int b = blockIdx.x, tid = threadIdx.x;
  if (b < TB1){
    // W1f[((tile*4+kt)*4+kq)*16+l15][e] = bf16(W1[k][col]), col=tile*16+l15,
    // k=kt*32+kq*8+e.  (tile<32, col<512, k<128)
    int idx = b*256 + tid;
    int e   = idx & 7;
    int l15 = (idx>>3) & 15;
    int kq  = (idx>>7) & 3;
    int kt  = (idx>>9) & 3;
    int tile= idx >> 11;
    int col = tile*16 + l15;
    int k   = kt*32 + kq*8 + e;
    W1f[idx] = (unsigned short)f2bf(W1[(size_t)k*512 + col]);
    return;
  }
  if (b < TB1 + TB2){
    // W2f[((tile*16+kt)*4+kq)*16+l15][e] = bf16(W2[k][col]), col=tile*16+l15,
    // k=kt*32+kq*8+e.  (tile<8, col<128, k<512)
    int idx = (b-TB1)*256 + tid;
    int e   = idx & 7;
    int l15 = (idx>>3) & 15;
    int kq  = (idx>>7) & 3;
    int kt  = (idx>>9) & 15;
    int tile= idx >> 13;
    int col = tile*16 + l15;
    int k   = kt*32 + kq*8 + e;
    W2f[idx] = (unsigned short)f2bf(W2[(size_t)k*128 + col]);
    return;
  }
  if (b < TB1 + TB2 + WTB){
    // wtil[v*128+k] = sum_c W1[k, (v&3)*128+c]*att{s|d}[(v&3),c]; 32 thr/output
    int o = (b-TB1-TB2)*8 + (tid>>5);               // 0..1023
    int c32 = tid & 31;
    int v = o >> 7, k = o & 127, h = v & 3;
    const float* av = (v < 4) ? (att1_s + h*128) : (att1_d + h*128);
    const float* wr = W1 + (size_t)k*512 + h*128;
    float p = wr[c32]*av[c32] + wr[c32+32]*av[c32+32]
            + wr[c32+64]*av[c32+64] + wr[c32+96]*av[c32+96];
    #pragma unroll
    for (int o2=1;o2<32;o2<<=1) p += __shfl_xor(p, o2);
    if (c32 == 0) wtil[o] = p;
    return;
  }
  int idx = (b - TB1 - TB2 - WTB)*256 + tid;        // zero cnt
  if (idx < N_NODES) cnt[idx] = 0;
}

// ---- mega kernel: ELL build (atomic slots) + input LN + fp32 att1 logits ----
static constexpr int EBL = (ETOT + 255)/256;        // 1329 edge blocks
static constexpr int LNB = N_NODES/4;               // 5000 LN blocks (4 rows ea)
__global__ __launch_bounds__(256) void k_build_mega(
    const int* __restrict__ ei, int* __restrict__ cnt, int* __restrict__ ell,
    const float* __restrict__ x, const float* __restrict__ g_in,
    const float* __restrict__ b_in, const float* __restrict__ wtil,
    unsigned* __restrict__ h0b, float4* __restrict__ als4, float4* __restrict__ ald4) {
  int b = blockIdx.x, tid = threadIdx.x;
  if (b < EBL){                                     // ELL scatter (deg<=64 w.h.p.)
    int e = b*256 + tid;
    int s, d;
    if (e < N_EDGES){ s = ei[e]; d = ei[N_EDGES+e]; }
    else if (e < ETOT){ s = e - N_EDGES; d = s; }
    else return;
    int pos = atomicAdd(&cnt[d], 1);
    if (pos < 64) ell[d*64 + pos] = s;
    return;
  }
  // LN over 128-ch rows -> bf16 h0b; logits als/ald = h0 . w~ (fp32 exact)
  int row = (b - EBL)*4 + (tid>>6);
  int t = tid & 63;
  float2 v = ((const float2*)(x + (size_t)row*128))[t];
  float s = v.x + v.y;
  float q = v.x*v.x + v.y*v.y;
  #pragma unroll
  for (int o=32;o>0;o>>=1){ s += __shfl_down(s,o); q += __shfl_down(q,o); }
  s = __shfl(s,0); q = __shfl(q,0);
  float mu = s*(1.f/128.f);
  float var = q*(1.f/128.f) - mu*mu;
  float rs = rsqrtf(var+LN_EPS);
  float d0 = v.x-mu, d1 = v.y-mu;
  float2 gg = ((const float2*)g_in)[t];
  float2 bb = ((const float2*)b_in)[t];
  float y0 = d0*rs*gg.x+bb.x;
  float y1 = d1*rs*gg.y+bb.y;
  h0b[(size_t)row*64 + t] = packbf2(y0,y1);
  float ps[4], pd[4];
  #pragma unroll
  for (int h=0;h<4;h++){
    float2 ws = ((const float2*)(wtil + h*128))[t];
    float2 wd = ((const float2*)(wtil + (4+h)*128))[t];
    ps[h] = y0*ws.x + y1*ws.y;
    pd[h] = y0*wd.x + y1*wd.y;
  }
  #pragma unroll
  for (int o=1;o<64;o<<=1){
    #pragma unroll
    for (int h=0;h<4;h++){ ps[h]+=__shfl_xor(ps[h],o); pd[h]+=__shfl_xor(pd[h],o); }
  }
  if (t==0){
    als4[row] = make_float4(ps[0],ps[1],ps[2],ps[3]);
    ald4[row] = make_float4(pd[0],pd[1],pd[2],pd[3]);
  }
}

// ---- GAT1 Part 1: aggregation only. 1 wave = 1 dst, zero barriers. ----
__global__ __launch_bounds__(256) void k_gat1_agg(
    const unsigned* __restrict__ h0,                 // [N][64] uint = [N,128] bf16
    const float4* __restrict__ als4, const float4* __restrict__ ald4, // [N]
    const int* __restrict__ cnt, const int* __restrict__ ell,
    unsigned* __restrict__ agg)                      // [N][256] uint = [N,512] bf16
{
  int wave = threadIdx.x>>6, lane = threadIdx.x&63;
  int d = blockIdx.x*4 + wave;
  __shared__ float4 alphaW4[4][64];
  __shared__ int   srcW[4][64];

  int deg = min(cnt[d],64);
  int s0 = ell[d*64 + lane];                         // unconditional; masked below
  float4 ad_ = ald4[d];
  s0 = (lane < deg) ? s0 : 0;
  float4 as_ = als4[s0];
  float e0=0.f,e1=0.f,e2=0.f,e3=0.f;
  if (lane < deg){
    e0 = __expf(lrelu02(as_.x+ad_.x));
    e1 = __expf(lrelu02(as_.y+ad_.y));
    e2 = __expf(lrelu02(as_.z+ad_.z));
    e3 = __expf(lrelu02(as_.w+ad_.w));
  }
  srcW[wave][lane] = s0;
  alphaW4[wave][lane] = make_float4(e0,e1,e2,e3);
  float q0=e0,q1=e1,q2=e2,q3=e3;
  #pragma unroll
  for (int o=1;o<64;o<<=1){
    q0+=__shfl_xor(q0,o); q1+=__shfl_xor(q1,o);
    q2+=__shfl_xor(q2,o); q3+=__shfl_xor(q3,o);
  }
  float inv[4] = {1.f/q0, 1.f/q1, 1.f/q2, 1.f/q3};

  f32x2 accP0={0.f,0.f}, accP1={0.f,0.f}, accP2={0.f,0.f}, accP3={0.f,0.f};
  int degR = (deg + 7) & ~7;

  auto load8 = [&](int j, unsigned* vv){
    int4 A = *(const int4*)&srcW[wave][j];
    int4 B = *(const int4*)&srcW[wave][j+4];
    vv[0] = h0[(unsigned)A.x*64u + lane];
    vv[1] = h0[(unsigned)A.y*64u + lane];
    vv[2] = h0[(unsigned)A.z*64u + lane];
    vv[3] = h0[(unsigned)A.w*64u + lane];
    vv[4] = h0[(unsigned)B.x*64u + lane];
    vv[5] = h0[(unsigned)B.y*64u + lane];
    vv[6] = h0[(unsigned)B.z*64u + lane];
    vv[7] = h0[(unsigned)B.w*64u + lane];
  };
  auto fma8 = [&](int j, const unsigned* vv){
    #pragma unroll
    for (int i=0;i<8;i++){
      float4 a = alphaW4[wave][j+i];                 // ONE b128 broadcast/edge
      f32x2 a01 = {a.x, a.y}, a23 = {a.z, a.w};
      f32x2 p   = {bflo(vv[i]), bfhi(vv[i])};
      pkfma_lo(accP0, a01, p);                       // {h0,h1} x lo
      pkfma_lo(accP1, a23, p);                       // {h2,h3} x lo
      pkfma_hi(accP2, a01, p);                       // {h0,h1} x hi
      pkfma_hi(accP3, a23, p);                       // {h2,h3} x hi
    }
  };

  unsigned v[8], vn[8];
  load8(0, v);
  int j = 0;
  for (; j+8 < degR; j+=8){
    load8(j+8, vn);                                  // next batch in flight...
    fma8(j, v);                                      // ...during this compute
    #pragma unroll
    for (int i=0;i<8;i++) v[i] = vn[i];
  }
  fma8(j, v);                                        // epilogue batch

  // normalize; lane owns ch pair (2*lane, 2*lane+1) per head; bf16 pack
  unsigned* arow = agg + (size_t)d*256;
  arow[0*64 + lane] = packbf2(accP0.x*inv[0], accP2.x*inv[0]);
  arow[1*64 + lane] = packbf2(accP0.y*inv[1], accP2.y*inv[1]);
  arow[2*64 + lane] = packbf2(accP1.x*inv[2], accP3.x*inv[2]);
  arow[3*64 + lane] = packbf2(accP1.y*inv[3], accP3.y*inv[3]);
}

// ---- GAT1 Part 2: W1-proj MFMA + LN(512)/GELU + GEMM2 + att2 logits.
// r21: B-operands from fragment-major W1f/W2f -> contiguous 1KB wave-loads. ----
__global__ __launch_bounds__(512) void k_gat1_mlp(
    const unsigned* __restrict__ agg,                // [N][256] uint
    const float* __restrict__ bias1, const float* __restrict__ g1, const float* __restrict__ b1,
    const unsigned short* __restrict__ W1f,          // fragment-major
    const unsigned short* __restrict__ W2f,          // fragment-major
    const float* __restrict__ att2_s, const float* __restrict__ att2_d, // [128]
    unsigned short* __restrict__ xh2b,               // [N,128] bf16
    float* __restrict__ als2, float* __restrict__ ald2) // [N]
{
  __shared__ unsigned short h1s[16*520];
  __shared__ float scrA[8][16], scrB[8][16];
  __shared__ float scrS[8][16], scrD[8][16];
  int dstbase = blockIdx.x*16;
  int tid = threadIdx.x, wave = tid>>6, lane = tid&63;
  int kq = lane>>4, l15 = lane&15;

  // ---- Phase B: W1 projection; wave covers cols [wave*64,+64), head = wave>>1 ----
  f32x4 acc1[4] = {};
  {
    const uint4* Agg4 = (const uint4*)agg;           // row stride 64 uint4
    const uint4* W1f4 = (const uint4*)W1f;
    int h = wave>>1;
    #pragma unroll
    for (int kt=0; kt<4; kt++){
      BF8 fh;
      fh.u4 = Agg4[(size_t)(dstbase + l15)*64 + h*16 + kt*4 + kq];
      #pragma unroll
      for (int ct=0; ct<4; ct++){
        int tile = wave*4 + ct;                      // col tile (16 cols)
        BF8 fb; fb.u4 = W1f4[((tile*4 + kt)*4 + kq)*16 + l15]; // 1KB/wave contig
        acc1[ct] = __builtin_amdgcn_mfma_f32_16x16x32_bf16(fh.v, fb.v, acc1[ct], 0,0,0);
      }
    }
  }
  // epilogue: bias + LN(512) + GELU; single-pass sum+sumsq -> ONE barrier
  float vloc[4][4];
  float sum_r[4] = {0,0,0,0}, sq_r[4] = {0,0,0,0};
  #pragma unroll
  for (int ct=0; ct<4; ct++){
    int col = wave*64 + ct*16 + l15;
    float bb = bias1[col];
    #pragma unroll
    for (int r=0;r<4;r++){
      float v = acc1[ct][r] + bb;
      vloc[ct][r] = v;
      sum_r[r] += v;
      sq_r[r]  += v*v;
    }
  }
  #pragma unroll
  for (int o=1;o<16;o<<=1)
    #pragma unroll
    for (int r=0;r<4;r++){ sum_r[r] += __shfl_xor(sum_r[r], o); sq_r[r] += __shfl_xor(sq_r[r], o); }
  if (l15 == 0){
    #pragma unroll
    for (int r=0;r<4;r++){ scrA[wave][kq*4+r] = sum_r[r]; scrB[wave][kq*4+r] = sq_r[r]; }
  }
  __syncthreads();
  #pragma unroll
  for (int r=0;r<4;r++){
    int m = kq*4+r;
    float s_ = 0.f, vs = 0.f;
    #pragma unroll
    for (int w=0;w<8;w++){ s_ += scrA[w][m]; vs += scrB[w][m]; }
    float mu = s_*(1.f/512.f);
    float var = vs*(1.f/512.f) - mu*mu;
    float rsv = rsqrtf(var+LN_EPS);
    #pragma unroll
    for (int ct=0; ct<4; ct++){
      int col = wave*64 + ct*16 + l15;
      float y = gelu_ex((vloc[ct][r]-mu)*rsv*g1[col] + b1[col]);
      h1s[(size_t)m*520 + col] = (unsigned short)f2bf(y);
    }
  }
  __syncthreads();

  // ---- Phase C: fused GEMM2 (wave covers out-cols [wave*16, +16)); K=512 ----
  f32x4 acc2 = {};
  const uint4* h1s4 = (const uint4*)h1s;
  const uint4* W2f4 = (const uint4*)W2f;
  int colc = wave*16 + l15;
  #pragma unroll
  for (int kt=0; kt<16; kt++){
    BF8 fa; fa.u4 = h1s4[(size_t)l15*65 + kt*4 + kq];
    BF8 fb; fb.u4 = W2f4[((wave*16 + kt)*4 + kq)*16 + l15]; // 1KB/wave contig
    acc2 = __builtin_amdgcn_mfma_f32_16x16x32_bf16(fa.v, fb.v, acc2, 0,0,0);
  }
  float ps[4], pd[4];
  {
    float ws = att2_s[colc], wd = att2_d[colc];
    #pragma unroll
    for (int r2=0; r2<4; r2++){
      float vv = acc2[r2];
      xh2b[(size_t)(dstbase + kq*4 + r2)*128 + colc] = (unsigned short)f2bf(vv);
      ps[r2] = vv*ws; pd[r2] = vv*wd;
    }
  }
  #pragma unroll
  for (int o=1;o<16;o<<=1){
    #pragma unroll
    for (int r2=0;r2<4;r2++){ ps[r2]+=__shfl_xor(ps[r2],o); pd[r2]+=__shfl_xor(pd[r2],o); }
  }
  if (l15 == 0){
    #pragma unroll
    for (int r2=0;r2<4;r2++){
      scrS[wave][kq*4+r2] = ps[r2];
      scrD[wave][kq*4+r2] = pd[r2];
    }
  }
  __syncthreads();
  if (tid < 16){
    float ss = 0.f, sd = 0.f;
    #pragma unroll
    for (int w=0;w<8;w++){ ss += scrS[w][tid]; sd += scrD[w][tid]; }
    als2[dstbase+tid] = ss;
    ald2[dstbase+tid] = sd;
  }
}

// -- GAT layer 2: unchanged from r19 (2-deep pipelined gather, den hoisted,
//    pk_fma, LDS-broadcast projection, Wo direct loads). --
__global__ __launch_bounds__(256) void k_gat2_final(
    const unsigned* __restrict__ xh,                 // [N,64] uint = [N,128] bf16
    const float* __restrict__ als, const float* __restrict__ ald, // [N]
    const int* __restrict__ cnt, const int* __restrict__ ell,
    const float* __restrict__ bias2, const float* __restrict__ g2, const float* __restrict__ b2,
    const float* __restrict__ Wo, const float* __restrict__ bo,
    float* __restrict__ out)                         // [N,32]
{
  int wave = threadIdx.x>>6, t = threadIdx.x&63;
  int d = blockIdx.x*4 + wave;
  __shared__ float alphaS[4][64];
  __shared__ int   srcS[4][64];
  __shared__ float yS[4][128];
  int deg = min(cnt[d], 64);
  int s0 = ell[d*64 + t];                            // unconditional; masked below
  float add = ald[d];
  s0 = (t < deg) ? s0 : 0;
  float lg = als[s0] + add;
  float ex = (t < deg) ? __expf(lrelu02(lg)) : 0.f;
  alphaS[wave][t] = ex;
  srcS[wave][t] = s0;

  // den reduction BEFORE the gather (independent of the loop)
  float den = ex;
  #pragma unroll
  for (int o=32;o>0;o>>=1) den += __shfl_down(den,o);
  den = __shfl(den,0);
  float inv = 1.f/den;

  f32x2 accP = {0.f, 0.f};                           // {lo-ch, hi-ch}
  int degR = (deg + 7) & ~7;

  auto load8 = [&](int j, unsigned* uu){
    int4 A = *(const int4*)&srcS[wave][j];
    int4 B = *(const int4*)&srcS[wave][j+4];
    uu[0] = xh[(unsigned)A.x*64u + t];
    uu[1] = xh[(unsigned)A.y*64u + t];
    uu[2] = xh[(unsigned)A.z*64u + t];
    uu[3] = xh[(unsigned)A.w*64u + t];
    uu[4] = xh[(unsigned)B.x*64u + t];
    uu[5] = xh[(unsigned)B.y*64u + t];
    uu[6] = xh[(unsigned)B.z*64u + t];
    uu[7] = xh[(unsigned)B.w*64u + t];
  };
  auto fma8 = [&](int j, const unsigned* uu){
    float4 aA = *(const float4*)&alphaS[wave][j];
    float4 aB = *(const float4*)&alphaS[wave][j+4];
    f32x2 aXY = {aA.x, aA.y}, aZW = {aA.z, aA.w};
    f32x2 bXY = {aB.x, aB.y}, bZW = {aB.z, aB.w};
    f32x2 v0 = {bflo(uu[0]), bfhi(uu[0])};
    f32x2 v1 = {bflo(uu[1]), bfhi(uu[1])};
    f32x2 v2 = {bflo(uu[2]), bfhi(uu[2])};
    f32x2 v3 = {bflo(uu[3]), bfhi(uu[3])};
    f32x2 v4 = {bflo(uu[4]), bfhi(uu[4])};
    f32x2 v5 = {bflo(uu[5]), bfhi(uu[5])};
    f32x2 v6 = {bflo(uu[6]), bfhi(uu[6])};
    f32x2 v7 = {bflo(uu[7]), bfhi(uu[7])};
    pkfma_lo(accP, v0, aXY);                         // += v0 * aA.x
    pkfma_hi(accP, v1, aXY);                         // += v1 * aA.y
    pkfma_lo(accP, v2, aZW);
    pkfma_hi(accP, v3, aZW);
    pkfma_lo(accP, v4, bXY);
    pkfma_hi(accP, v5, bXY);
    pkfma_lo(accP, v6, bZW);
    pkfma_hi(accP, v7, bZW);
  };

  unsigned u[8], un[8];
  load8(0, u);
  int j = 0;
  for (; j+8 < degR; j+=8){
    load8(j+8, un);                                  // next batch in flight...
    fma8(j, u);                                      // ...during this compute
    #pragma unroll
    for (int i=0;i<8;i++) u[i] = un[i];
  }
  fma8(j, u);                                        // epilogue batch

  float2 bb = ((const float2*)bias2)[t];
  float v0 = accP.x*inv + bb.x;
  float v1 = accP.y*inv + bb.y;

  // LN(128) — single merged (sum, sumsq) tree
  float s1 = v0+v1, q = v0*v0+v1*v1;
  #pragma unroll
  for (int o=32;o>0;o>>=1){ s1 += __shfl_down(s1,o); q += __shfl_down(q,o); }
  s1 = __shfl(s1,0); q = __shfl(q,0);
  float mu = s1*(1.f/128.f);
  float var = q*(1.f/128.f) - mu*mu;
  float rs = rsqrtf(var+LN_EPS);
  float d0=v0-mu, d1=v1-mu;
  float2 gg = ((const float2*)g2)[t];
  float2 b4 = ((const float2*)b2)[t];
  float y0 = gelu_ex(d0*rs*gg.x+b4.x);
  float y1 = gelu_ex(d1*rs*gg.y+b4.y);

  // projection (128->32): stage y in wave-private LDS, broadcast-read back.
  ((float2*)&yS[wave][0])[t] = make_float2(y0,y1);   // lane t owns ch 2t,2t+1
  int half = t>>5, c = t&31;
  const float4* y4 = (const float4*)&yS[wave][half*64];
  f32x2 partP = {0.f, 0.f};                          // {even-ch, odd-ch} partials
  #pragma unroll
  for (int k=0;k<16;k++){
    float4 yv = y4[k];                               // broadcast per half-wave
    int ch = half*64 + k*4;
    f32x2 w01 = {Wo[(ch+0)*32 + c], Wo[(ch+1)*32 + c]};
    f32x2 w23 = {Wo[(ch+2)*32 + c], Wo[(ch+3)*32 + c]};
    f32x2 yxy = {yv.x, yv.y}, yzw = {yv.z, yv.w};
    pkfma(partP, yxy, w01);
    pkfma(partP, yzw, w23);
  }
  float part = partP.x + partP.y;
  part += __shfl_down(part, 32);                     // lanes 0..31 hold full dot
  float logit = part + bo[c];

  // log_softmax over 32 (lanes 0..31)
  float mx = logit;
  #pragma unroll
  for (int o=16;o>0;o>>=1) mx = fmaxf(mx, __shfl_xor(mx,o));
  float se = __expf(logit-mx);
  #pragma unroll
  for (int o=16;o>0;o>>=1) se += __shfl_xor(se,o);
  float lse = mx + __logf(se);
  if (t < 32) out[(size_t)d*32+t] = logit - lse;
}

extern "C" void kernel_launch(void* const* d_in, const int* in_sizes, int n_in,
                              void* d_out, int out_size, void* d_ws, size_t ws_size,
                              hipStream_t stream) {
  const float* x      = (const float*)d_in[0];
  const int*   ei     = (const int*)d_in[1];
  const float* g_in   = (const float*)d_in[2];
  const float* b_in   = (const float*)d_in[3];
  const float* W1     = (const float*)d_in[4];
  const float* att1_s = (const float*)d_in[5];
  const float* att1_d = (const float*)d_in[6];
  const float* bias1  = (const float*)d_in[7];
  const float* g1     = (const float*)d_in[8];
  const float* b1     = (const float*)d_in[9];
  const float* W2     = (const float*)d_in[10];
  const float* att2_s = (const float*)d_in[11];
  const float* att2_d = (const float*)d_in[12];
  const float* bias2  = (const float*)d_in[13];
  const float* g2     = (const float*)d_in[14];
  const float* b2     = (const float*)d_in[15];
  const float* Wo     = (const float*)d_in[16];
  const float* bo     = (const float*)d_in[17];
  float* out = (float*)d_out;

  char* ws = (char*)d_ws;
  size_t off = 0;
  auto alloc = [&](size_t bytes)->char*{
    char* p = ws + off; off += (bytes + 255) & ~(size_t)255; return p;
  };
  unsigned* h0b   = (unsigned*)alloc((size_t)N_NODES*128*2);       // LN(x) bf16 table
  unsigned short* xh2b = (unsigned short*)alloc((size_t)N_NODES*128*2); // fused GEMM2 out bf16
  unsigned* aggb  = (unsigned*)alloc((size_t)N_NODES*512*2);       // GAT1 agg bf16 [N][512]
  float*    als1  = (float*)alloc((size_t)N_NODES*4*4);
  float*    ald1  = (float*)alloc((size_t)N_NODES*4*4);
  float*    als2  = (float*)alloc((size_t)N_NODES*4);
  float*    ald2  = (float*)alloc((size_t)N_NODES*4);
  int*      cnt   = (int*)alloc((size_t)N_NODES*4);
  int*      ell   = (int*)alloc((size_t)N_NODES*64*4);             // ELL adjacency
  unsigned short* W1f = (unsigned short*)alloc((size_t)512*128*2); // fragment-major
  unsigned short* W2f = (unsigned short*)alloc((size_t)128*512*2); // fragment-major
  float*    wtil  = (float*)alloc((size_t)8*128*4);                // fused logit vecs

  // 1. fragment-major weight packs + parallel w~ + zero cnt
  k_prep<<<TB1 + TB2 + WTB + ZCB,256,0,stream>>>(W1, W2, att1_s, att1_d,
                                                 W1f, W2f, wtil, cnt);
  // 2. ELL build + input LN + fp32 att1 logits
  k_build_mega<<<EBL + LNB,256,0,stream>>>(ei, cnt, ell, x, g_in, b_in, wtil,
                                           h0b, (float4*)als1, (float4*)ald1);
  // 3a. GAT1 aggregation (barrier-free, 1 wave/dst)
  k_gat1_agg<<<N_NODES/4,256,0,stream>>>(h0b,
      (const float4*)als1, (const float4*)ald1, cnt, ell, aggb);
  // 3b. GAT1 MLP: W1-proj MFMA + LN/GELU + GEMM2 + att2 logits
  k_gat1_mlp<<<N_NODES/16,512,0,stream>>>(aggb,
      bias1, g1, b1, W1f, W2f, att2_s, att2_d, xh2b, als2, ald2);
  // 4. GAT layer 2 + Wo projection + log_softmax
  k_gat2_final<<<N_NODES/4,256,0,stream>>>((const unsigned*)xh2b, als2, ald2,
      cnt, ell, bias2, g2, b2, Wo, bo, out);
}